// Round 13
// baseline (1346.727 us; speedup 1.0000x reference)
//
#include <hip/hip_runtime.h>
#include <hip/hip_bf16.h>

// ---------------- problem constants ----------------
#define Nn 8000      // nodes
#define Ee 32000     // edges
#define Bb 64        // graphs
#define Dembed 200
#define Ttok 20
#define Mp 8192      // padded node count
#define K1 4096      // padded 4000 (layer-1 in dim)
#define K1L 4032     // K-loop trim: first mult of 64 >= 4000
#define K2 6144      // padded 6000 (layer-1/2 out dim)
#define K2L 6016     // K-loop trim: first mult of 64 >= 6000
#define L1p 3072     // padded 3000
#define LCHUNK 256   // split-K chunk for lin1
#define NCH 24       // ceil(6000/256)

// GEMM tile geometry (256^2, 8 waves x 128x64, single-barrier tile loop) — R12 proven
#define GBM 256
#define GBN 256
#define GBK 64
#define ABUF (GBM * GBK)          // 16384 els (A region per buffer)
#define BUFE (2 * ABUF)           // 32768 els per buffer (A+B)

#define LRELU(v) ((v) > 0.f ? (v) : 0.01f * (v))

typedef __attribute__((ext_vector_type(4))) float f32x4;
typedef __attribute__((ext_vector_type(8))) short s16x8;
typedef __attribute__((ext_vector_type(4))) short s16x4;

#define GLL16(gp, lp) __builtin_amdgcn_global_load_lds( \
    (const __attribute__((address_space(1))) void*)(gp), \
    (__attribute__((address_space(3))) void*)(lp), 16, 0, 0)

__device__ __forceinline__ float b2f(short s) {
    union { unsigned u; float f; } c;
    c.u = ((unsigned)(unsigned short)s) << 16;
    return c.f;
}
__device__ __forceinline__ short f2b(float f) {
    __hip_bfloat16 h = __float2bfloat16(f);  // RNE
    return __builtin_bit_cast(short, h);
}

// ---------------- degree / dinv / CSR build ----------------
__global__ void k_deg(const int* __restrict__ dst, int* __restrict__ indeg) {
    int e = blockIdx.x * 256 + threadIdx.x;
    if (e < Ee) atomicAdd(&indeg[dst[e]], 1);
}

// single-block exclusive scan of indeg -> rowptr, plus dinv (fused)
__global__ __launch_bounds__(1024)
void k_scan(const int* __restrict__ indeg, int* __restrict__ rowptr,
            float* __restrict__ dinv, int n)
{
    __shared__ int sums[1024];
    const int t = threadIdx.x;
    const int base = t * 8;
    int loc[8];
    int s = 0;
#pragma unroll
    for (int j = 0; j < 8; ++j) {
        int v = (base + j < n) ? indeg[base + j] : 0;
        loc[j] = s; s += v;
    }
    sums[t] = s;
    __syncthreads();
    for (int off = 1; off < 1024; off <<= 1) {
        int v = sums[t];
        int add = (t >= off) ? sums[t - off] : 0;
        __syncthreads();
        sums[t] = v + add;
        __syncthreads();
    }
    const int prev = (t == 0) ? 0 : sums[t - 1];
#pragma unroll
    for (int j = 0; j < 8; ++j)
        if (base + j < n) {
            rowptr[base + j] = prev + loc[j];
            dinv[base + j] = rsqrtf((float)indeg[base + j] + 1.0f);
        }
    if (t == 1023) rowptr[n] = sums[1023];
}

__global__ void k_fill(const int* __restrict__ src, const int* __restrict__ dst,
                       const int* __restrict__ rowptr, int* __restrict__ fillc,
                       int* __restrict__ csr) {
    int e = blockIdx.x * 256 + threadIdx.x;
    if (e < Ee) {
        int d = dst[e];
        int pos = rowptr[d] + atomicAdd(&fillc[d], 1);
        csr[pos] = src[e];
    }
}

// ---------------- fused gather+agg1: Ah0[i] = dinv_i^2*emb(x_i) + sum_s w_si*emb(x_s) ----------------
// emb is 4MB (L2-resident); never materializes h0. fp32 accumulation directly from emb
// (more accurate than prior bf16 round-trip). Thread t owns cols {t*8+g*2048 : g=0,1},
// 8 consecutive cols per group; 200|4000 and 8|cols so each group straddles <=1 token
// boundary (precomputed tk0/off0/nsplit). Neighbor tok lists chunk-preloaded to LDS.
__global__ __launch_bounds__(256)
void k_gagg(const int* __restrict__ x, const float* __restrict__ emb,
            const float* __restrict__ dinv, const int* __restrict__ rowptr,
            const int* __restrict__ csr, short* __restrict__ Ah0)
{
    const int i = blockIdx.x;
    const int tid = threadIdx.x;
    __shared__ float s_w[64];
    __shared__ int s_tok[64 * Ttok];
    __shared__ int s_tok0[Ttok];

    // per-thread column geometry (constant across neighbors)
    int cg[2], tk0[2], off0[2], nsp[2];
    bool valid[2];
#pragma unroll
    for (int g = 0; g < 2; ++g) {
        cg[g] = tid * 8 + g * 2048;
        valid[g] = (cg[g] < Ttok * Dembed);   // < 4000
        tk0[g] = cg[g] / Dembed;
        off0[g] = cg[g] - tk0[g] * Dembed;
        int r = Dembed - off0[g];
        nsp[g] = r > 8 ? 8 : r;
    }

    const float di = dinv[i];
    const float wself = di * di;

    if (tid < Ttok) s_tok0[tid] = x[i * Ttok + tid];
    __syncthreads();

    float acc[2][8] = {};
    // self term
#pragma unroll
    for (int g = 0; g < 2; ++g) {
        if (!valid[g]) continue;
        const float* r0 = emb + (long)s_tok0[tk0[g]] * Dembed + off0[g];
        for (int j = 0; j < nsp[g]; ++j) acc[g][j] = wself * r0[j];
        if (nsp[g] < 8) {
            const float* r1 = emb + (long)s_tok0[tk0[g] + 1] * Dembed + (off0[g] - Dembed);
            for (int j = nsp[g]; j < 8; ++j) acc[g][j] = wself * r1[j];
        }
    }

    const int e0 = rowptr[i], e1 = rowptr[i + 1];
    for (int eb = e0; eb < e1; eb += 64) {
        const int cnt = min(64, e1 - eb);
        __syncthreads();
        if (tid < cnt) {
            int s = csr[eb + tid];
            s_w[tid] = dinv[s] * di;
        }
        __syncthreads();
        // preload tok lists for this chunk (need csr again; reread via s? use global)
        for (int f = tid; f < cnt * Ttok; f += 256) {
            int e = f / Ttok;
            int tk = f - e * Ttok;
            s_tok[f] = x[(long)csr[eb + e] * Ttok + tk];
        }
        __syncthreads();
        for (int e = 0; e < cnt; ++e) {
            const float w = s_w[e];
            const int* te = s_tok + e * Ttok;
#pragma unroll
            for (int g = 0; g < 2; ++g) {
                if (!valid[g]) continue;
                const float* r0 = emb + (long)te[tk0[g]] * Dembed + off0[g];
                for (int j = 0; j < nsp[g]; ++j) acc[g][j] += w * r0[j];
                if (nsp[g] < 8) {
                    const float* r1 = emb + (long)te[tk0[g] + 1] * Dembed + (off0[g] - Dembed);
                    for (int j = nsp[g]; j < 8; ++j) acc[g][j] += w * r1[j];
                }
            }
        }
    }

#pragma unroll
    for (int g = 0; g < 2; ++g) {
        s16x8 o;
#pragma unroll
        for (int j = 0; j < 8; ++j) o[j] = f2b(acc[g][j]);   // invalid groups write zeros
        *(s16x8*)(Ah0 + (long)i * K1 + cg[g]) = o;
    }
}

// ---------------- normalized aggregation (LDS-preloaded neighbor lists) ----------------
template<int NG>
__global__ __launch_bounds__(256)
void k_agg(const short* __restrict__ Hin, short* __restrict__ Hout,
           const float* __restrict__ dinv, const int* __restrict__ rowptr,
           const int* __restrict__ csr, int Wp)
{
    const int i = blockIdx.x;
    const int tid = threadIdx.x;
    __shared__ int   s_idx[64];
    __shared__ float s_w[64];
    const float di = dinv[i];
    const float wself = di * di;
    const long rowi = (long)i * Wp;
    float acc[NG * 8];
#pragma unroll
    for (int gI = 0; gI < NG; ++gI) {
        s16x8 v = *(const s16x8*)(Hin + rowi + gI * 2048 + tid * 8);
#pragma unroll
        for (int j = 0; j < 8; ++j) acc[gI * 8 + j] = wself * b2f(v[j]);
    }
    const int e0 = rowptr[i], e1 = rowptr[i + 1];
    for (int eb = e0; eb < e1; eb += 64) {
        const int cnt = min(64, e1 - eb);
        __syncthreads();
        if (tid < cnt) {
            int s = csr[eb + tid];
            s_idx[tid] = s;
            s_w[tid] = dinv[s] * di;
        }
        __syncthreads();
        for (int e = 0; e < cnt; ++e) {
            const long rows = (long)s_idx[e] * Wp;
            const float w = s_w[e];
#pragma unroll
            for (int gI = 0; gI < NG; ++gI) {
                s16x8 v = *(const s16x8*)(Hin + rows + gI * 2048 + tid * 8);
#pragma unroll
                for (int j = 0; j < 8; ++j) acc[gI * 8 + j] += w * b2f(v[j]);
            }
        }
    }
#pragma unroll
    for (int gI = 0; gI < NG; ++gI) {
        s16x8 o;
#pragma unroll
        for (int j = 0; j < 8; ++j) o[j] = f2b(acc[gI * 8 + j]);
        *(s16x8*)(Hout + rowi + gI * 2048 + tid * 8) = o;
    }
}

// ---------------- transpose + fp32->bf16 (vectorized 8B stores) ----------------
__global__ __launch_bounds__(256)
void k_transpose(const float* __restrict__ In, short* __restrict__ Out,
                 int K, int N, int Kp, int Np)
{
    __shared__ float tile[32][33];
    const int k0 = blockIdx.x * 32;
    const int n0 = blockIdx.y * 32;
    const int tid = threadIdx.x;
    const int ln = tid & 31, lk = tid >> 5;   // load: n fast (coalesced)
#pragma unroll
    for (int kk = lk; kk < 32; kk += 8) {
        int k = k0 + kk, n = n0 + ln;
        tile[kk][ln] = (k < K && n < N) ? In[(long)k * N + n] : 0.f;
    }
    __syncthreads();
    const int kq = tid & 7, nn = tid >> 3;    // store: 4 consecutive k per thread
    s16x4 o;
#pragma unroll
    for (int j = 0; j < 4; ++j) o[j] = f2b(tile[kq * 4 + j][nn]);
    *(s16x4*)(&Out[(long)(n0 + nn) * Kp + k0 + kq * 4]) = o;
}

// ---------------- 256^2 pipelined bf16 MFMA GEMM (R12 proven) ----------------
__global__ __launch_bounds__(512, 2)
void k_gemm8w(const short* __restrict__ A, const short* __restrict__ Bt,
              short* __restrict__ C, const float* __restrict__ bias,
              int K, int Kloop, int Np, int Nreal, int nbx)
{
    __shared__ short lds[2 * BUFE];   // 128 KiB

    const int tid  = threadIdx.x;
    const int lane = tid & 63;
    const int wid  = tid >> 6;
    const int wm   = wid >> 2;   // 0..1
    const int wn   = wid & 3;    // 0..3

    // T1: XCD-aware block swizzle (gridDim.x % 8 == 0)
    const int cpx = (int)gridDim.x >> 3;
    const int bid = (int)blockIdx.x;
    const int swz = (bid & 7) * cpx + (bid >> 3);
    const int bx = swz % nbx;          // N tile
    const int by = swz / nbx;          // M tile

    // ---- staging (per thread), pre-swizzled global source, linear LDS dest ----
    const int rq = tid >> 3;                                // 0..63 (row within chunk)
    const int kq = ((tid & 7) << 3) ^ ((rq & 7) << 3);      // swizzled k source
    const short* Abase = A  + ((long)by * GBM + rq) * K + kq;
    const short* Bbase = Bt + ((long)bx * GBN + rq) * K + kq;

#define ST2(bb, t2, base, ldoff, c0_, c1_) do { \
    const short* g0_ = (base) + (long)((c0_) * 64) * K + (long)(t2) * GBK; \
    const short* g1_ = (base) + (long)((c1_) * 64) * K + (long)(t2) * GBK; \
    GLL16(g0_, lds + (bb) * BUFE + (ldoff) + (c0_) * 4096 + tid * 8); \
    GLL16(g1_, lds + (bb) * BUFE + (ldoff) + (c1_) * 4096 + tid * 8); \
  } while (0)

    // ---- fragment read addresses (swizzled) ----
    const int fr  = lane & 15;
    const int kb8 = (lane >> 4) << 3;          // 0,8,16,24
    const int xm  = (fr & 7) << 3;
    const int ck0 = kb8 ^ xm;                  // kk=0 column term
    const int ck1 = (32 + kb8) ^ xm;           // kk=32 column term
    const int aoff = (wm * 128 + fr) * 64;     // + m*1024 + ck
    const int boff = ABUF + (wn * 64 + fr) * 64;  // + n*1024 + ck

    f32x4 acc[8][4] = {};
    s16x8 av_a[4], av_b[4], bv1[4], bv3[4];

    const int NT = Kloop >> 6;

    // ---- prologue: stage tile 0 into buf0 ----
    ST2(0, 0, Bbase, ABUF, 0, 1);
    ST2(0, 0, Bbase, ABUF, 2, 3);
    ST2(0, 0, Abase, 0,    0, 2);
    ST2(0, 0, Abase, 0,    1, 3);
    asm volatile("s_waitcnt vmcnt(0)" ::: "memory");
    __builtin_amdgcn_s_barrier();

    int buf = 0;
    for (int t = 0; t < NT; ++t) {
        const short* lb = lds + buf * BUFE;
        const int nb = buf ^ 1;
        const bool pf = (t + 1 < NT);

        // Q1 reads (B kk0 + A m0-3 kk0)
#pragma unroll
        for (int n = 0; n < 4; ++n) bv1[n] = *(const s16x8*)(lb + boff + n * 1024 + ck0);
#pragma unroll
        for (int m = 0; m < 4; ++m) av_a[m] = *(const s16x8*)(lb + aoff + m * 1024 + ck0);
        if (pf) ST2(nb, t + 1, Bbase, ABUF, 0, 1);
        // Q2 reads (A m4-7 kk0)
#pragma unroll
        for (int m = 0; m < 4; ++m) av_b[m] = *(const s16x8*)(lb + aoff + (4 + m) * 1024 + ck0);
        // MFMA Q1
        __builtin_amdgcn_s_setprio(1);
#pragma unroll
        for (int m = 0; m < 4; ++m)
#pragma unroll
            for (int n = 0; n < 4; ++n)
                acc[m][n] = __builtin_amdgcn_mfma_f32_16x16x32_bf16(av_a[m], bv1[n], acc[m][n], 0, 0, 0);
        __builtin_amdgcn_s_setprio(0);
        if (pf) ST2(nb, t + 1, Bbase, ABUF, 2, 3);
        // Q3 reads (B kk32 + A m4-7 kk32) — av_a reused (dead after Q1)
#pragma unroll
        for (int n = 0; n < 4; ++n) bv3[n] = *(const s16x8*)(lb + boff + n * 1024 + ck1);
#pragma unroll
        for (int m = 0; m < 4; ++m) av_a[m] = *(const s16x8*)(lb + aoff + (4 + m) * 1024 + ck1);
        // MFMA Q2
        __builtin_amdgcn_s_setprio(1);
#pragma unroll
        for (int m = 0; m < 4; ++m)
#pragma unroll
            for (int n = 0; n < 4; ++n)
                acc[4 + m][n] = __builtin_amdgcn_mfma_f32_16x16x32_bf16(av_b[m], bv1[n], acc[4 + m][n], 0, 0, 0);
        __builtin_amdgcn_s_setprio(0);
        if (pf) ST2(nb, t + 1, Abase, 0, 0, 2);
        // Q4 reads (A m0-3 kk32) — av_b reused (dead after Q2)
#pragma unroll
        for (int m = 0; m < 4; ++m) av_b[m] = *(const s16x8*)(lb + aoff + m * 1024 + ck1);
        // MFMA Q3
        __builtin_amdgcn_s_setprio(1);
#pragma unroll
        for (int m = 0; m < 4; ++m)
#pragma unroll
            for (int n = 0; n < 4; ++n)
                acc[4 + m][n] = __builtin_amdgcn_mfma_f32_16x16x32_bf16(av_a[m], bv3[n], acc[4 + m][n], 0, 0, 0);
        __builtin_amdgcn_s_setprio(0);
        if (pf) ST2(nb, t + 1, Abase, 0, 1, 3);
        // MFMA Q4
        __builtin_amdgcn_s_setprio(1);
#pragma unroll
        for (int m = 0; m < 4; ++m)
#pragma unroll
            for (int n = 0; n < 4; ++n)
                acc[m][n] = __builtin_amdgcn_mfma_f32_16x16x32_bf16(av_b[m], bv3[n], acc[m][n], 0, 0, 0);
        __builtin_amdgcn_s_setprio(0);

        // boundary: drain (issued ~full tile ago) + single barrier
        asm volatile("s_waitcnt vmcnt(0)" ::: "memory");
        __builtin_amdgcn_s_barrier();
        buf = nb;
    }

    // ---- epilogue: bias + leaky + bf16 store, n-INNERMOST for line coalescing ----
    const int rr = (lane >> 4) << 2;
    long colv[4];
    float bb[4];
#pragma unroll
    for (int n = 0; n < 4; ++n) {
        colv[n] = (long)bx * GBN + wn * 64 + n * 16 + fr;
        bb[n] = (colv[n] < Nreal) ? bias[colv[n]] : 0.f;
    }
#pragma unroll
    for (int m = 0; m < 8; ++m) {
#pragma unroll
        for (int j = 0; j < 4; ++j) {
            const long rowoff = ((long)by * GBM + wm * 128 + m * 16 + rr + j) * Np;
#pragma unroll
            for (int n = 0; n < 4; ++n) {
                float v = acc[m][n][j] + bb[n];
                v = LRELU(v);
                C[rowoff + colv[n]] = f2b(v);
            }
        }
    }
#undef ST2
}

// ---------------- batch boundaries ----------------
__global__ void k_bptr(const int* __restrict__ batch, int* __restrict__ bptr) {
    int i = blockIdx.x * 256 + threadIdx.x;
    if (i >= Nn) return;
    int b = batch[i];
    int pb = (i == 0) ? -1 : batch[i - 1];
    for (int bb = pb + 1; bb <= b; ++bb) bptr[bb] = i;
    if (i == Nn - 1)
        for (int bb = b + 1; bb <= Bb; ++bb) bptr[bb] = Nn;
}

// ---------------- global max pool (vectorized: 8 cols/thread) ----------------
__global__ __launch_bounds__(256)
void k_pool(const short* __restrict__ h2, const int* __restrict__ bptr,
            float* __restrict__ g, int Wp) {
    const int c8 = blockIdx.x * 256 + threadIdx.x;   // group of 8 cols
    const int b = blockIdx.y;
    const short* base = h2 + (long)c8 * 8;
    float mx[8];
#pragma unroll
    for (int j = 0; j < 8; ++j) mx[j] = -INFINITY;
    const int i0 = bptr[b], i1 = bptr[b + 1];
    for (int i = i0; i < i1; ++i) {
        s16x8 v = *(const s16x8*)(base + (long)i * Wp);
#pragma unroll
        for (int j = 0; j < 8; ++j) mx[j] = fmaxf(mx[j], b2f(v[j]));
    }
#pragma unroll
    for (int j = 0; j < 8; ++j) g[(long)b * Wp + c8 * 8 + j] = mx[j];
}

// ---------------- linear1 split-K ----------------
__global__ __launch_bounds__(256)
void k_lin1_part(const float* __restrict__ g, const float* __restrict__ Wl1,
                 float* __restrict__ part) {
    __shared__ float gs[64][65];
    __shared__ float Ws[64][64];
    const int tid = threadIdx.x;
    const int jc = blockIdx.x * 64;
    const int k0 = blockIdx.y * LCHUNK;
    const int k1 = min(6000, k0 + LCHUNK);
    const int r = tid & 63;
    const int jb = (tid >> 6) * 16;
    float acc[16] = {};
    for (int kc = k0; kc < k1; kc += 64) {
#pragma unroll
        for (int p = 0; p < 16; ++p) {
            int el = p * 256 + tid;
            int rr = el >> 6, kk = el & 63;
            gs[rr][kk] = (kc + kk < k1) ? g[rr * K2 + kc + kk] : 0.f;
            Ws[rr][kk] = (kc + rr < k1 && jc + kk < 3000)
                         ? Wl1[(long)(kc + rr) * 3000 + jc + kk] : 0.f;
        }
        __syncthreads();
#pragma unroll
        for (int k = 0; k < 64; ++k) {
            float a = gs[r][k];
#pragma unroll
            for (int jj = 0; jj < 16; ++jj)
                acc[jj] += a * Ws[k][jb + jj];
        }
        __syncthreads();
    }
    float* prow = part + ((long)blockIdx.y * 64 + r) * L1p + jc + jb;
#pragma unroll
    for (int jj = 0; jj < 16; ++jj) prow[jj] = acc[jj];
}

__global__ __launch_bounds__(256)
void k_lin1_red(const float* __restrict__ part, const float* __restrict__ bl1,
                float* __restrict__ g1) {
    int idx = blockIdx.x * 256 + threadIdx.x;
    if (idx >= 64 * 3000) return;
    int r = idx / 3000;
    int c = idx - r * 3000;
    float s = bl1[c];
#pragma unroll
    for (int p = 0; p < NCH; ++p)
        s += part[((long)p * 64 + r) * L1p + c];
    g1[r * L1p + c] = LRELU(s);
}

// ---------------- linear2 ----------------
__global__ __launch_bounds__(256)
void k_lin2(const float* __restrict__ g1, const float* __restrict__ Wl2,
            const float* __restrict__ bl2, float* __restrict__ out) {
    const int r = blockIdx.x;
    const int tid = threadIdx.x;
    float a0 = 0, a1 = 0, a2 = 0, a3 = 0;
    for (int k = tid; k < 3000; k += 256) {
        float gv = g1[r * L1p + k];
        const float* w = Wl2 + (long)k * 4;
        a0 += gv * w[0]; a1 += gv * w[1]; a2 += gv * w[2]; a3 += gv * w[3];
    }
    __shared__ float red[256][4];
    red[tid][0] = a0; red[tid][1] = a1; red[tid][2] = a2; red[tid][3] = a3;
    __syncthreads();
    for (int s = 128; s > 0; s >>= 1) {
        if (tid < s) {
            red[tid][0] += red[tid + s][0]; red[tid][1] += red[tid + s][1];
            red[tid][2] += red[tid + s][2]; red[tid][3] += red[tid + s][3];
        }
        __syncthreads();
    }
    if (tid < 4) {
        float v = red[0][tid] + bl2[tid];
        out[r * 4 + tid] = LRELU(v);
    }
}

// ---------------- launch ----------------
extern "C" void kernel_launch(void* const* d_in, const int* in_sizes, int n_in,
                              void* d_out, int out_size, void* d_ws, size_t ws_size,
                              hipStream_t stream)
{
    const int*   x     = (const int*)d_in[0];
    const int*   ei    = (const int*)d_in[1];
    const int*   batch = (const int*)d_in[2];
    const float* emb   = (const float*)d_in[3];
    const float* W1    = (const float*)d_in[4];
    const float* b1    = (const float*)d_in[5];
    const float* W2    = (const float*)d_in[6];
    const float* b2    = (const float*)d_in[7];
    const float* Wl1   = (const float*)d_in[8];
    const float* bl1   = (const float*)d_in[9];
    const float* Wl2   = (const float*)d_in[10];
    const float* bl2   = (const float*)d_in[11];
    float* out = (float*)d_out;

    const int* esrc = ei;
    const int* edst = ei + Ee;

    const size_t MiB = 1ull << 20;
    char* W = (char*)d_ws;
    short* Ah0b = (short*)(W + 64 * MiB);   // [8192,4096] bf16, 64 MiB
    short* W2t  = (short*)(W + 96 * MiB);   // [6144,6144] bf16, 72 MiB (after GEMM1)
    short* W1t  = (short*)(W + 128 * MiB);  // [6144,4096] bf16, 48 MiB
    short* h1b  = (short*)(W + 176 * MiB);  // [8192,6144] bf16, 96 MiB
    short* Ah1b = (short*)(W + 0);          // [8192,6144] bf16, 96 MiB (after GEMM1)
    short* h2b  = h1b;                      // reuse
    float* part = (float*)(W + 0);          // [24][64][3072] f32 (after pool)
    char* S = W + 272 * MiB;
    int*   indeg  = (int*)(S);                 // 32 KB
    int*   fillc  = (int*)(S + 32 * 1024);     // 32 KB (adjacent -> single memset)
    int*   rowptr = (int*)(S + 64 * 1024);
    float* dinv   = (float*)(S + 96 * 1024);
    int*   csr    = (int*)(S + 128 * 1024);
    int*   bptr   = (int*)(S + 256 * 1024);
    float* g      = (float*)(S + 320 * 1024);
    float* g1     = (float*)(S + 320 * 1024 + 2 * MiB);

    hipMemsetAsync(indeg, 0, 64 * 1024, stream);   // indeg + fillc in one shot

    k_deg<<<(Ee + 255) / 256, 256, 0, stream>>>(edst, indeg);
    k_scan<<<1, 1024, 0, stream>>>(indeg, rowptr, dinv, Nn);
    k_fill<<<(Ee + 255) / 256, 256, 0, stream>>>(esrc, edst, rowptr, fillc, csr);

    const int nbx = K2 / GBN;               // 24
    const int nwg = nbx * (Mp / GBM);       // 24*32 = 768, % 8 == 0

    k_gagg<<<Nn, 256, 0, stream>>>(x, emb, dinv, rowptr, csr, Ah0b);
    k_transpose<<<dim3(K1 / 32, K2 / 32), 256, 0, stream>>>(W1, W1t, 4000, 6000, K1, K2);
    k_gemm8w<<<nwg, 512, 0, stream>>>(Ah0b, W1t, h1b, b1, K1, K1L, K2, 6000, nbx);

    k_transpose<<<dim3(K2 / 32, K2 / 32), 256, 0, stream>>>(W2, W2t, 6000, 6000, K2, K2);
    k_agg<3><<<Nn, 256, 0, stream>>>(h1b, Ah1b, dinv, rowptr, csr, K2);
    k_gemm8w<<<nwg, 512, 0, stream>>>(Ah1b, W2t, h2b, b2, K2, K2L, K2, 6000, nbx);

    k_bptr<<<(Nn + 255) / 256, 256, 0, stream>>>(batch, bptr);
    k_pool<<<dim3(K2 / 2048, Bb), 256, 0, stream>>>(h2b, bptr, g, K2);
    k_lin1_part<<<dim3(L1p / 64, NCH), 256, 0, stream>>>(g, Wl1, part);
    k_lin1_red<<<(64 * 3000 + 255) / 256, 256, 0, stream>>>(part, bl1, g1);
    k_lin2<<<Bb, 256, 0, stream>>>(g1, Wl2, bl2, out);
}

// Round 14
// 1267.926 us; speedup vs baseline: 1.0621x; 1.0621x over previous
//
#include <hip/hip_runtime.h>
#include <hip/hip_bf16.h>

// ---------------- problem constants ----------------
#define Nn 8000      // nodes
#define Ee 32000     // edges
#define Bb 64        // graphs
#define Dembed 200
#define Ttok 20
#define Mp 8192      // padded node count
#define K1 4096      // padded 4000 (layer-1 in dim)
#define K1L 4032     // K-loop trim: first mult of 64 >= 4000
#define K2 6144      // padded 6000 (layer-1/2 out dim)
#define K2L 6016     // K-loop trim: first mult of 64 >= 6000
#define L1p 3072     // padded 3000
#define LCHUNK 256   // split-K chunk for lin1
#define NCH 24       // ceil(6000/256)

// GEMM tile geometry (256^2, 8 waves x 128x64, single-barrier tile loop) — R12 proven
#define GBM 256
#define GBN 256
#define GBK 64
#define ABUF (GBM * GBK)          // 16384 els (A region per buffer)
#define BUFE (2 * ABUF)           // 32768 els per buffer (A+B)

#define LRELU(v) ((v) > 0.f ? (v) : 0.01f * (v))

typedef __attribute__((ext_vector_type(4))) float f32x4;
typedef __attribute__((ext_vector_type(8))) short s16x8;
typedef __attribute__((ext_vector_type(4))) short s16x4;

#define GLL16(gp, lp) __builtin_amdgcn_global_load_lds( \
    (const __attribute__((address_space(1))) void*)(gp), \
    (__attribute__((address_space(3))) void*)(lp), 16, 0, 0)

__device__ __forceinline__ float b2f(short s) {
    union { unsigned u; float f; } c;
    c.u = ((unsigned)(unsigned short)s) << 16;
    return c.f;
}
__device__ __forceinline__ short f2b(float f) {
    __hip_bfloat16 h = __float2bfloat16(f);  // RNE
    return __builtin_bit_cast(short, h);
}

// ---------------- degree / dinv / CSR build ----------------
__global__ void k_deg(const int* __restrict__ dst, int* __restrict__ indeg) {
    int e = blockIdx.x * 256 + threadIdx.x;
    if (e < Ee) atomicAdd(&indeg[dst[e]], 1);
}

// single-block exclusive scan of indeg -> rowptr, plus dinv (fused)
__global__ __launch_bounds__(1024)
void k_scan(const int* __restrict__ indeg, int* __restrict__ rowptr,
            float* __restrict__ dinv, int n)
{
    __shared__ int sums[1024];
    const int t = threadIdx.x;
    const int base = t * 8;
    int loc[8];
    int s = 0;
#pragma unroll
    for (int j = 0; j < 8; ++j) {
        int v = (base + j < n) ? indeg[base + j] : 0;
        loc[j] = s; s += v;
    }
    sums[t] = s;
    __syncthreads();
    for (int off = 1; off < 1024; off <<= 1) {
        int v = sums[t];
        int add = (t >= off) ? sums[t - off] : 0;
        __syncthreads();
        sums[t] = v + add;
        __syncthreads();
    }
    const int prev = (t == 0) ? 0 : sums[t - 1];
#pragma unroll
    for (int j = 0; j < 8; ++j)
        if (base + j < n) {
            rowptr[base + j] = prev + loc[j];
            dinv[base + j] = rsqrtf((float)indeg[base + j] + 1.0f);
        }
    if (t == 1023) rowptr[n] = sums[1023];
}

__global__ void k_fill(const int* __restrict__ src, const int* __restrict__ dst,
                       const int* __restrict__ rowptr, int* __restrict__ fillc,
                       int* __restrict__ csr) {
    int e = blockIdx.x * 256 + threadIdx.x;
    if (e < Ee) {
        int d = dst[e];
        int pos = rowptr[d] + atomicAdd(&fillc[d], 1);
        csr[pos] = src[e];
    }
}

// ---------------- fused gather+agg1: Ah0[i] = dinv_i^2*emb(x_i) + sum_s w_si*emb(x_s) ----------------
// emb is 4MB (L2-resident); never materializes h0. fp32 accumulation directly from emb.
// Since 8 | 200, every 8-col group lies inside ONE token row and is exactly two aligned
// float4 loads (the R13 scalar boundary-split path was dead code and kept loads scalar).
__global__ __launch_bounds__(256)
void k_gagg(const int* __restrict__ x, const float* __restrict__ emb,
            const float* __restrict__ dinv, const int* __restrict__ rowptr,
            const int* __restrict__ csr, short* __restrict__ Ah0)
{
    const int i = blockIdx.x;
    const int tid = threadIdx.x;
    __shared__ float s_w[64];
    __shared__ int s_tok[64 * Ttok];
    __shared__ int s_tok0[Ttok];

    int cg[2], tk0[2], off0[2];
    bool valid[2];
#pragma unroll
    for (int g = 0; g < 2; ++g) {
        cg[g] = tid * 8 + g * 2048;
        valid[g] = (cg[g] < Ttok * Dembed);   // < 4000
        tk0[g] = cg[g] / Dembed;
        off0[g] = cg[g] - tk0[g] * Dembed;    // multiple of 8; 200-off0 >= 8 always
    }

    const float di = dinv[i];
    const float wself = di * di;

    if (tid < Ttok) s_tok0[tid] = x[i * Ttok + tid];
    __syncthreads();

    float acc[2][8] = {};
#pragma unroll
    for (int g = 0; g < 2; ++g) {
        if (!valid[g]) continue;
        const f32x4* r = (const f32x4*)(emb + (long)s_tok0[tk0[g]] * Dembed + off0[g]);
        f32x4 v0 = r[0], v1 = r[1];
#pragma unroll
        for (int j = 0; j < 4; ++j) { acc[g][j] = wself * v0[j]; acc[g][4 + j] = wself * v1[j]; }
    }

    const int e0 = rowptr[i], e1 = rowptr[i + 1];
    for (int eb = e0; eb < e1; eb += 64) {
        const int cnt = min(64, e1 - eb);
        __syncthreads();
        if (tid < cnt) {
            int s = csr[eb + tid];
            s_w[tid] = dinv[s] * di;
        }
        __syncthreads();
        for (int f = tid; f < cnt * Ttok; f += 256) {
            int e = f / Ttok;
            int tk = f - e * Ttok;
            s_tok[f] = x[(long)csr[eb + e] * Ttok + tk];
        }
        __syncthreads();
        for (int e = 0; e < cnt; ++e) {
            const float w = s_w[e];
            const int* te = s_tok + e * Ttok;
#pragma unroll
            for (int g = 0; g < 2; ++g) {
                if (!valid[g]) continue;
                const f32x4* r = (const f32x4*)(emb + (long)te[tk0[g]] * Dembed + off0[g]);
                f32x4 v0 = r[0], v1 = r[1];
#pragma unroll
                for (int j = 0; j < 4; ++j) { acc[g][j] += w * v0[j]; acc[g][4 + j] += w * v1[j]; }
            }
        }
    }

#pragma unroll
    for (int g = 0; g < 2; ++g) {
        s16x8 o;
#pragma unroll
        for (int j = 0; j < 8; ++j) o[j] = f2b(acc[g][j]);   // invalid groups write zeros
        *(s16x8*)(Ah0 + (long)i * K1 + cg[g]) = o;
    }
}

// ---------------- normalized aggregation (LDS-preloaded lists, 2x unrolled rows) ----------------
template<int NG>
__global__ __launch_bounds__(256)
void k_agg(const short* __restrict__ Hin, short* __restrict__ Hout,
           const float* __restrict__ dinv, const int* __restrict__ rowptr,
           const int* __restrict__ csr, int Wp)
{
    const int i = blockIdx.x;
    const int tid = threadIdx.x;
    __shared__ int   s_idx[64];
    __shared__ float s_w[64];
    const float di = dinv[i];
    const float wself = di * di;
    const long rowi = (long)i * Wp;
    float acc[NG * 8];
#pragma unroll
    for (int gI = 0; gI < NG; ++gI) {
        s16x8 v = *(const s16x8*)(Hin + rowi + gI * 2048 + tid * 8);
#pragma unroll
        for (int j = 0; j < 8; ++j) acc[gI * 8 + j] = wself * b2f(v[j]);
    }
    const int e0 = rowptr[i], e1 = rowptr[i + 1];
    for (int eb = e0; eb < e1; eb += 64) {
        const int cnt = min(64, e1 - eb);
        __syncthreads();
        if (tid < cnt) {
            int s = csr[eb + tid];
            s_idx[tid] = s;
            s_w[tid] = dinv[s] * di;
        }
        __syncthreads();
        int e = 0;
        for (; e + 1 < cnt; e += 2) {          // 2x unroll: 2*NG loads in flight
            const long ra = (long)s_idx[e] * Wp;
            const long rb = (long)s_idx[e + 1] * Wp;
            const float wa = s_w[e], wb = s_w[e + 1];
            s16x8 va[NG], vb[NG];
#pragma unroll
            for (int gI = 0; gI < NG; ++gI) {
                va[gI] = *(const s16x8*)(Hin + ra + gI * 2048 + tid * 8);
                vb[gI] = *(const s16x8*)(Hin + rb + gI * 2048 + tid * 8);
            }
#pragma unroll
            for (int gI = 0; gI < NG; ++gI)
#pragma unroll
                for (int j = 0; j < 8; ++j)
                    acc[gI * 8 + j] += wa * b2f(va[gI][j]) + wb * b2f(vb[gI][j]);
        }
        if (e < cnt) {
            const long ra = (long)s_idx[e] * Wp;
            const float wa = s_w[e];
#pragma unroll
            for (int gI = 0; gI < NG; ++gI) {
                s16x8 v = *(const s16x8*)(Hin + ra + gI * 2048 + tid * 8);
#pragma unroll
                for (int j = 0; j < 8; ++j) acc[gI * 8 + j] += wa * b2f(v[j]);
            }
        }
    }
#pragma unroll
    for (int gI = 0; gI < NG; ++gI) {
        s16x8 o;
#pragma unroll
        for (int j = 0; j < 8; ++j) o[j] = f2b(acc[gI * 8 + j]);
        *(s16x8*)(Hout + rowi + gI * 2048 + tid * 8) = o;
    }
}

// ---------------- transpose + fp32->bf16 (vectorized 8B stores) ----------------
__global__ __launch_bounds__(256)
void k_transpose(const float* __restrict__ In, short* __restrict__ Out,
                 int K, int N, int Kp, int Np)
{
    __shared__ float tile[32][33];
    const int k0 = blockIdx.x * 32;
    const int n0 = blockIdx.y * 32;
    const int tid = threadIdx.x;
    const int ln = tid & 31, lk = tid >> 5;   // load: n fast (coalesced)
#pragma unroll
    for (int kk = lk; kk < 32; kk += 8) {
        int k = k0 + kk, n = n0 + ln;
        tile[kk][ln] = (k < K && n < N) ? In[(long)k * N + n] : 0.f;
    }
    __syncthreads();
    const int kq = tid & 7, nn = tid >> 3;    // store: 4 consecutive k per thread
    s16x4 o;
#pragma unroll
    for (int j = 0; j < 4; ++j) o[j] = f2b(tile[kq * 4 + j][nn]);
    *(s16x4*)(&Out[(long)(n0 + nn) * Kp + k0 + kq * 4]) = o;
}

// ---------------- 256^2 pipelined bf16 MFMA GEMM (R12 + earlier stage issue) ----------------
// BM=BN=256 BK=64, 512 threads (8 waves, 2M x 4N), wave tile 128x64 (acc[8][4]),
// 16x16x32 MFMA, single barrier per K-tile, K-loop trim, coalesced epilogue.
// Stage issues shifted one slot earlier (B23 pre-MFMA1, A02 post-Q3-reads, A13
// post-Q4-reads): the last GLL now has ~2 MFMA quadrants (~1240 cyc) before the
// boundary vmcnt(0) -> drain stall (was ~300 cyc, issue only 1 quadrant ahead) gone.
__global__ __launch_bounds__(512, 2)
void k_gemm8w(const short* __restrict__ A, const short* __restrict__ Bt,
              short* __restrict__ C, const float* __restrict__ bias,
              int K, int Kloop, int Np, int Nreal, int nbx)
{
    __shared__ short lds[2 * BUFE];   // 128 KiB

    const int tid  = threadIdx.x;
    const int lane = tid & 63;
    const int wid  = tid >> 6;
    const int wm   = wid >> 2;   // 0..1
    const int wn   = wid & 3;    // 0..3

    // T1: XCD-aware block swizzle (gridDim.x % 8 == 0)
    const int cpx = (int)gridDim.x >> 3;
    const int bid = (int)blockIdx.x;
    const int swz = (bid & 7) * cpx + (bid >> 3);
    const int bx = swz % nbx;          // N tile
    const int by = swz / nbx;          // M tile

    // ---- staging (per thread), pre-swizzled global source, linear LDS dest ----
    const int rq = tid >> 3;                                // 0..63 (row within chunk)
    const int kq = ((tid & 7) << 3) ^ ((rq & 7) << 3);      // swizzled k source
    const short* Abase = A  + ((long)by * GBM + rq) * K + kq;
    const short* Bbase = Bt + ((long)bx * GBN + rq) * K + kq;

#define ST2(bb, t2, base, ldoff, c0_, c1_) do { \
    const short* g0_ = (base) + (long)((c0_) * 64) * K + (long)(t2) * GBK; \
    const short* g1_ = (base) + (long)((c1_) * 64) * K + (long)(t2) * GBK; \
    GLL16(g0_, lds + (bb) * BUFE + (ldoff) + (c0_) * 4096 + tid * 8); \
    GLL16(g1_, lds + (bb) * BUFE + (ldoff) + (c1_) * 4096 + tid * 8); \
  } while (0)

    // ---- fragment read addresses (swizzled) ----
    const int fr  = lane & 15;
    const int kb8 = (lane >> 4) << 3;          // 0,8,16,24
    const int xm  = (fr & 7) << 3;
    const int ck0 = kb8 ^ xm;                  // kk=0 column term
    const int ck1 = (32 + kb8) ^ xm;           // kk=32 column term
    const int aoff = (wm * 128 + fr) * 64;     // + m*1024 + ck
    const int boff = ABUF + (wn * 64 + fr) * 64;  // + n*1024 + ck

    f32x4 acc[8][4] = {};
    s16x8 av_a[4], av_b[4], bv1[4], bv3[4];

    const int NT = Kloop >> 6;

    // ---- prologue: stage tile 0 into buf0 ----
    ST2(0, 0, Bbase, ABUF, 0, 1);
    ST2(0, 0, Bbase, ABUF, 2, 3);
    ST2(0, 0, Abase, 0,    0, 2);
    ST2(0, 0, Abase, 0,    1, 3);
    asm volatile("s_waitcnt vmcnt(0)" ::: "memory");
    __builtin_amdgcn_s_barrier();

    int buf = 0;
    for (int t = 0; t < NT; ++t) {
        const short* lb = lds + buf * BUFE;
        const int nb = buf ^ 1;
        const bool pf = (t + 1 < NT);

        // Q1 reads (B kk0 + A m0-3 kk0); issue B01,B23(t+1)
#pragma unroll
        for (int n = 0; n < 4; ++n) bv1[n] = *(const s16x8*)(lb + boff + n * 1024 + ck0);
#pragma unroll
        for (int m = 0; m < 4; ++m) av_a[m] = *(const s16x8*)(lb + aoff + m * 1024 + ck0);
        if (pf) ST2(nb, t + 1, Bbase, ABUF, 0, 1);
        // Q2 reads (A m4-7 kk0)
#pragma unroll
        for (int m = 0; m < 4; ++m) av_b[m] = *(const s16x8*)(lb + aoff + (4 + m) * 1024 + ck0);
        if (pf) ST2(nb, t + 1, Bbase, ABUF, 2, 3);
        // MFMA Q1
        __builtin_amdgcn_s_setprio(1);
#pragma unroll
        for (int m = 0; m < 4; ++m)
#pragma unroll
            for (int n = 0; n < 4; ++n)
                acc[m][n] = __builtin_amdgcn_mfma_f32_16x16x32_bf16(av_a[m], bv1[n], acc[m][n], 0, 0, 0);
        __builtin_amdgcn_s_setprio(0);
        // Q3 reads (B kk32 + A m4-7 kk32); issue A02(t+1)
#pragma unroll
        for (int n = 0; n < 4; ++n) bv3[n] = *(const s16x8*)(lb + boff + n * 1024 + ck1);
#pragma unroll
        for (int m = 0; m < 4; ++m) av_a[m] = *(const s16x8*)(lb + aoff + (4 + m) * 1024 + ck1);
        if (pf) ST2(nb, t + 1, Abase, 0, 0, 2);
        // MFMA Q2
        __builtin_amdgcn_s_setprio(1);
#pragma unroll
        for (int m = 0; m < 4; ++m)
#pragma unroll
            for (int n = 0; n < 4; ++n)
                acc[4 + m][n] = __builtin_amdgcn_mfma_f32_16x16x32_bf16(av_b[m], bv1[n], acc[4 + m][n], 0, 0, 0);
        __builtin_amdgcn_s_setprio(0);
        // Q4 reads (A m0-3 kk32); issue A13(t+1) — 2 quadrants before the drain
#pragma unroll
        for (int m = 0; m < 4; ++m) av_b[m] = *(const s16x8*)(lb + aoff + m * 1024 + ck1);
        if (pf) ST2(nb, t + 1, Abase, 0, 1, 3);
        // MFMA Q3
        __builtin_amdgcn_s_setprio(1);
#pragma unroll
        for (int m = 0; m < 4; ++m)
#pragma unroll
            for (int n = 0; n < 4; ++n)
                acc[4 + m][n] = __builtin_amdgcn_mfma_f32_16x16x32_bf16(av_a[m], bv3[n], acc[4 + m][n], 0, 0, 0);
        __builtin_amdgcn_s_setprio(0);
        // MFMA Q4
        __builtin_amdgcn_s_setprio(1);
#pragma unroll
        for (int m = 0; m < 4; ++m)
#pragma unroll
            for (int n = 0; n < 4; ++n)
                acc[m][n] = __builtin_amdgcn_mfma_f32_16x16x32_bf16(av_b[m], bv3[n], acc[m][n], 0, 0, 0);
        __builtin_amdgcn_s_setprio(0);

        // boundary: drain (all issues >= 2 quadrants old) + single barrier
        asm volatile("s_waitcnt vmcnt(0)" ::: "memory");
        __builtin_amdgcn_s_barrier();
        buf = nb;
    }

    // ---- epilogue: bias + leaky + bf16 store, n-INNERMOST for line coalescing ----
    const int rr = (lane >> 4) << 2;
    long colv[4];
    float bb[4];
#pragma unroll
    for (int n = 0; n < 4; ++n) {
        colv[n] = (long)bx * GBN + wn * 64 + n * 16 + fr;
        bb[n] = (colv[n] < Nreal) ? bias[colv[n]] : 0.f;
    }
#pragma unroll
    for (int m = 0; m < 8; ++m) {
#pragma unroll
        for (int j = 0; j < 4; ++j) {
            const long rowoff = ((long)by * GBM + wm * 128 + m * 16 + rr + j) * Np;
#pragma unroll
            for (int n = 0; n < 4; ++n) {
                float v = acc[m][n][j] + bb[n];
                v = LRELU(v);
                C[rowoff + colv[n]] = f2b(v);
            }
        }
    }
#undef ST2
}

// ---------------- batch boundaries ----------------
__global__ void k_bptr(const int* __restrict__ batch, int* __restrict__ bptr) {
    int i = blockIdx.x * 256 + threadIdx.x;
    if (i >= Nn) return;
    int b = batch[i];
    int pb = (i == 0) ? -1 : batch[i - 1];
    for (int bb = pb + 1; bb <= b; ++bb) bptr[bb] = i;
    if (i == Nn - 1)
        for (int bb = b + 1; bb <= Bb; ++bb) bptr[bb] = Nn;
}

// ---------------- global max pool (vectorized: 8 cols/thread) ----------------
__global__ __launch_bounds__(256)
void k_pool(const short* __restrict__ h2, const int* __restrict__ bptr,
            float* __restrict__ g, int Wp) {
    const int c8 = blockIdx.x * 256 + threadIdx.x;   // group of 8 cols
    const int b = blockIdx.y;
    const short* base = h2 + (long)c8 * 8;
    float mx[8];
#pragma unroll
    for (int j = 0; j < 8; ++j) mx[j] = -INFINITY;
    const int i0 = bptr[b], i1 = bptr[b + 1];
    for (int i = i0; i < i1; ++i) {
        s16x8 v = *(const s16x8*)(base + (long)i * Wp);
#pragma unroll
        for (int j = 0; j < 8; ++j) mx[j] = fmaxf(mx[j], b2f(v[j]));
    }
#pragma unroll
    for (int j = 0; j < 8; ++j) g[(long)b * Wp + c8 * 8 + j] = mx[j];
}

// ---------------- linear1 split-K ----------------
__global__ __launch_bounds__(256)
void k_lin1_part(const float* __restrict__ g, const float* __restrict__ Wl1,
                 float* __restrict__ part) {
    __shared__ float gs[64][65];
    __shared__ float Ws[64][64];
    const int tid = threadIdx.x;
    const int jc = blockIdx.x * 64;
    const int k0 = blockIdx.y * LCHUNK;
    const int k1 = min(6000, k0 + LCHUNK);
    const int r = tid & 63;
    const int jb = (tid >> 6) * 16;
    float acc[16] = {};
    for (int kc = k0; kc < k1; kc += 64) {
#pragma unroll
        for (int p = 0; p < 16; ++p) {
            int el = p * 256 + tid;
            int rr = el >> 6, kk = el & 63;
            gs[rr][kk] = (kc + kk < k1) ? g[rr * K2 + kc + kk] : 0.f;
            Ws[rr][kk] = (kc + rr < k1 && jc + kk < 3000)
                         ? Wl1[(long)(kc + rr) * 3000 + jc + kk] : 0.f;
        }
        __syncthreads();
#pragma unroll
        for (int k = 0; k < 64; ++k) {
            float a = gs[r][k];
#pragma unroll
            for (int jj = 0; jj < 16; ++jj)
                acc[jj] += a * Ws[k][jb + jj];
        }
        __syncthreads();
    }
    float* prow = part + ((long)blockIdx.y * 64 + r) * L1p + jc + jb;
#pragma unroll
    for (int jj = 0; jj < 16; ++jj) prow[jj] = acc[jj];
}

__global__ __launch_bounds__(256)
void k_lin1_red(const float* __restrict__ part, const float* __restrict__ bl1,
                float* __restrict__ g1) {
    int idx = blockIdx.x * 256 + threadIdx.x;
    if (idx >= 64 * 3000) return;
    int r = idx / 3000;
    int c = idx - r * 3000;
    float s = bl1[c];
#pragma unroll
    for (int p = 0; p < NCH; ++p)
        s += part[((long)p * 64 + r) * L1p + c];
    g1[r * L1p + c] = LRELU(s);
}

// ---------------- linear2 ----------------
__global__ __launch_bounds__(256)
void k_lin2(const float* __restrict__ g1, const float* __restrict__ Wl2,
            const float* __restrict__ bl2, float* __restrict__ out) {
    const int r = blockIdx.x;
    const int tid = threadIdx.x;
    float a0 = 0, a1 = 0, a2 = 0, a3 = 0;
    for (int k = tid; k < 3000; k += 256) {
        float gv = g1[r * L1p + k];
        const float* w = Wl2 + (long)k * 4;
        a0 += gv * w[0]; a1 += gv * w[1]; a2 += gv * w[2]; a3 += gv * w[3];
    }
    __shared__ float red[256][4];
    red[tid][0] = a0; red[tid][1] = a1; red[tid][2] = a2; red[tid][3] = a3;
    __syncthreads();
    for (int s = 128; s > 0; s >>= 1) {
        if (tid < s) {
            red[tid][0] += red[tid + s][0]; red[tid][1] += red[tid + s][1];
            red[tid][2] += red[tid + s][2]; red[tid][3] += red[tid + s][3];
        }
        __syncthreads();
    }
    if (tid < 4) {
        float v = red[0][tid] + bl2[tid];
        out[r * 4 + tid] = LRELU(v);
    }
}

// ---------------- launch ----------------
extern "C" void kernel_launch(void* const* d_in, const int* in_sizes, int n_in,
                              void* d_out, int out_size, void* d_ws, size_t ws_size,
                              hipStream_t stream)
{
    const int*   x     = (const int*)d_in[0];
    const int*   ei    = (const int*)d_in[1];
    const int*   batch = (const int*)d_in[2];
    const float* emb   = (const float*)d_in[3];
    const float* W1    = (const float*)d_in[4];
    const float* b1    = (const float*)d_in[5];
    const float* W2    = (const float*)d_in[6];
    const float* b2    = (const float*)d_in[7];
    const float* Wl1   = (const float*)d_in[8];
    const float* bl1   = (const float*)d_in[9];
    const float* Wl2   = (const float*)d_in[10];
    const float* bl2   = (const float*)d_in[11];
    float* out = (float*)d_out;

    const int* esrc = ei;
    const int* edst = ei + Ee;

    const size_t MiB = 1ull << 20;
    char* W = (char*)d_ws;
    short* Ah0b = (short*)(W + 64 * MiB);   // [8192,4096] bf16, 64 MiB
    short* W2t  = (short*)(W + 96 * MiB);   // [6144,6144] bf16, 72 MiB (after GEMM1)
    short* W1t  = (short*)(W + 128 * MiB);  // [6144,4096] bf16, 48 MiB
    short* h1b  = (short*)(W + 176 * MiB);  // [8192,6144] bf16, 96 MiB
    short* Ah1b = (short*)(W + 0);          // [8192,6144] bf16, 96 MiB (after GEMM1)
    short* h2b  = h1b;                      // reuse
    float* part = (float*)(W + 0);          // [24][64][3072] f32 (after pool)
    char* S = W + 272 * MiB;
    int*   indeg  = (int*)(S);                 // 32 KB
    int*   fillc  = (int*)(S + 32 * 1024);     // 32 KB (adjacent -> single memset)
    int*   rowptr = (int*)(S + 64 * 1024);
    float* dinv   = (float*)(S + 96 * 1024);
    int*   csr    = (int*)(S + 128 * 1024);
    int*   bptr   = (int*)(S + 256 * 1024);
    float* g      = (float*)(S + 320 * 1024);
    float* g1     = (float*)(S + 320 * 1024 + 2 * MiB);

    hipMemsetAsync(indeg, 0, 64 * 1024, stream);   // indeg + fillc in one shot

    k_deg<<<(Ee + 255) / 256, 256, 0, stream>>>(edst, indeg);
    k_scan<<<1, 1024, 0, stream>>>(indeg, rowptr, dinv, Nn);
    k_fill<<<(Ee + 255) / 256, 256, 0, stream>>>(esrc, edst, rowptr, fillc, csr);

    const int nbx = K2 / GBN;               // 24
    const int nwg = nbx * (Mp / GBM);       // 24*32 = 768, % 8 == 0

    k_gagg<<<Nn, 256, 0, stream>>>(x, emb, dinv, rowptr, csr, Ah0b);
    k_transpose<<<dim3(K1 / 32, K2 / 32), 256, 0, stream>>>(W1, W1t, 4000, 6000, K1, K2);
    k_gemm8w<<<nwg, 512, 0, stream>>>(Ah0b, W1t, h1b, b1, K1, K1L, K2, 6000, nbx);

    k_transpose<<<dim3(K2 / 32, K2 / 32), 256, 0, stream>>>(W2, W2t, 6000, 6000, K2, K2);
    k_agg<3><<<Nn, 256, 0, stream>>>(h1b, Ah1b, dinv, rowptr, csr, K2);
    k_gemm8w<<<nwg, 512, 0, stream>>>(Ah1b, W2t, h2b, b2, K2, K2L, K2, 6000, nbx);

    k_bptr<<<(Nn + 255) / 256, 256, 0, stream>>>(batch, bptr);
    k_pool<<<dim3(K2 / 2048, Bb), 256, 0, stream>>>(h2b, bptr, g, K2);
    k_lin1_part<<<dim3(L1p / 64, NCH), 256, 0, stream>>>(g, Wl1, part);
    k_lin1_red<<<(64 * 3000 + 255) / 256, 256, 0, stream>>>(part, bl1, g1);
    k_lin2<<<Bb, 256, 0, stream>>>(g1, Wl2, bl2, out);
}

// Round 15
// 1227.367 us; speedup vs baseline: 1.0972x; 1.0330x over previous
//
#include <hip/hip_runtime.h>
#include <hip/hip_bf16.h>

// ---------------- problem constants ----------------
#define Nn 8000      // nodes
#define Ee 32000     // edges
#define Bb 64        // graphs
#define Dembed 200
#define Ttok 20
#define Mp 8192      // padded node count
#define K1 4096      // padded 4000 (layer-1 in dim)
#define K1L 4032     // K-loop trim: first mult of 64 >= 4000
#define K2 6144      // padded 6000 (layer-1/2 out dim)
#define K2L 6016     // K-loop trim: first mult of 64 >= 6000
#define L1p 3072     // padded 3000
#define LCHUNK 256   // split-K chunk for lin1
#define NCH 24       // ceil(6000/256)

// GEMM tile geometry (256^2, 8 waves x 128x64, single-barrier tile loop) — R14 proven
#define GBM 256
#define GBN 256
#define GBK 64
#define ABUF (GBM * GBK)          // 16384 els (A region per buffer)
#define BUFE (2 * ABUF)           // 32768 els per buffer (A+B)

#define LRELU(v) ((v) > 0.f ? (v) : 0.01f * (v))

typedef __attribute__((ext_vector_type(4))) float f32x4;
typedef __attribute__((ext_vector_type(8))) short s16x8;
typedef __attribute__((ext_vector_type(4))) short s16x4;

#define GLL16(gp, lp) __builtin_amdgcn_global_load_lds( \
    (const __attribute__((address_space(1))) void*)(gp), \
    (__attribute__((address_space(3))) void*)(lp), 16, 0, 0)

__device__ __forceinline__ float b2f(short s) {
    union { unsigned u; float f; } c;
    c.u = ((unsigned)(unsigned short)s) << 16;
    return c.f;
}
__device__ __forceinline__ short f2b(float f) {
    __hip_bfloat16 h = __float2bfloat16(f);  // RNE
    return __builtin_bit_cast(short, h);
}

// ---------------- degree / dinv / CSR build ----------------
__global__ void k_deg(const int* __restrict__ dst, int* __restrict__ indeg) {
    int e = blockIdx.x * 256 + threadIdx.x;
    if (e < Ee) atomicAdd(&indeg[dst[e]], 1);
}

// single-block exclusive scan of indeg -> rowptr, plus dinv (fused)
__global__ __launch_bounds__(1024)
void k_scan(const int* __restrict__ indeg, int* __restrict__ rowptr,
            float* __restrict__ dinv, int n)
{
    __shared__ int sums[1024];
    const int t = threadIdx.x;
    const int base = t * 8;
    int loc[8];
    int s = 0;
#pragma unroll
    for (int j = 0; j < 8; ++j) {
        int v = (base + j < n) ? indeg[base + j] : 0;
        loc[j] = s; s += v;
    }
    sums[t] = s;
    __syncthreads();
    for (int off = 1; off < 1024; off <<= 1) {
        int v = sums[t];
        int add = (t >= off) ? sums[t - off] : 0;
        __syncthreads();
        sums[t] = v + add;
        __syncthreads();
    }
    const int prev = (t == 0) ? 0 : sums[t - 1];
#pragma unroll
    for (int j = 0; j < 8; ++j)
        if (base + j < n) {
            rowptr[base + j] = prev + loc[j];
            dinv[base + j] = rsqrtf((float)indeg[base + j] + 1.0f);
        }
    if (t == 1023) rowptr[n] = sums[1023];
}

__global__ void k_fill(const int* __restrict__ src, const int* __restrict__ dst,
                       const int* __restrict__ rowptr, int* __restrict__ fillc,
                       int* __restrict__ csr) {
    int e = blockIdx.x * 256 + threadIdx.x;
    if (e < Ee) {
        int d = dst[e];
        int pos = rowptr[d] + atomicAdd(&fillc[d], 1);
        csr[pos] = src[e];
    }
}

// ---------------- fused gather+agg1 (2x neighbor unroll) ----------------
// Ah0[i] = dinv_i^2*emb(x_i) + sum_s w_si*emb(x_s); emb 4MB L2-resident; fp32 accum.
__global__ __launch_bounds__(256)
void k_gagg(const int* __restrict__ x, const float* __restrict__ emb,
            const float* __restrict__ dinv, const int* __restrict__ rowptr,
            const int* __restrict__ csr, short* __restrict__ Ah0)
{
    const int i = blockIdx.x;
    const int tid = threadIdx.x;
    __shared__ float s_w[64];
    __shared__ int s_tok[64 * Ttok];
    __shared__ int s_tok0[Ttok];

    int cg[2], tk0[2], off0[2];
    bool valid[2];
#pragma unroll
    for (int g = 0; g < 2; ++g) {
        cg[g] = tid * 8 + g * 2048;
        valid[g] = (cg[g] < Ttok * Dembed);   // < 4000
        tk0[g] = cg[g] / Dembed;
        off0[g] = cg[g] - tk0[g] * Dembed;    // multiple of 8; 200-off0 >= 8 always
    }

    const float di = dinv[i];
    const float wself = di * di;

    if (tid < Ttok) s_tok0[tid] = x[i * Ttok + tid];
    __syncthreads();

    float acc[2][8] = {};
#pragma unroll
    for (int g = 0; g < 2; ++g) {
        if (!valid[g]) continue;
        const f32x4* r = (const f32x4*)(emb + (long)s_tok0[tk0[g]] * Dembed + off0[g]);
        f32x4 v0 = r[0], v1 = r[1];
#pragma unroll
        for (int j = 0; j < 4; ++j) { acc[g][j] = wself * v0[j]; acc[g][4 + j] = wself * v1[j]; }
    }

    const int e0 = rowptr[i], e1 = rowptr[i + 1];
    for (int eb = e0; eb < e1; eb += 64) {
        const int cnt = min(64, e1 - eb);
        __syncthreads();
        if (tid < cnt) {
            int s = csr[eb + tid];
            s_w[tid] = dinv[s] * di;
        }
        __syncthreads();
        for (int f = tid; f < cnt * Ttok; f += 256) {
            int e = f / Ttok;
            int tk = f - e * Ttok;
            s_tok[f] = x[(long)csr[eb + e] * Ttok + tk];
        }
        __syncthreads();
        int e = 0;
        for (; e + 1 < cnt; e += 2) {      // 2x unroll: 4 f32x4 loads in flight per group
            const float wa = s_w[e], wb = s_w[e + 1];
            const int* ta = s_tok + e * Ttok;
            const int* tb = ta + Ttok;
#pragma unroll
            for (int g = 0; g < 2; ++g) {
                if (!valid[g]) continue;
                const f32x4* ra = (const f32x4*)(emb + (long)ta[tk0[g]] * Dembed + off0[g]);
                const f32x4* rb = (const f32x4*)(emb + (long)tb[tk0[g]] * Dembed + off0[g]);
                f32x4 a0 = ra[0], a1 = ra[1], b0 = rb[0], b1 = rb[1];
#pragma unroll
                for (int j = 0; j < 4; ++j) {
                    acc[g][j]     += wa * a0[j] + wb * b0[j];
                    acc[g][4 + j] += wa * a1[j] + wb * b1[j];
                }
            }
        }
        if (e < cnt) {
            const float w = s_w[e];
            const int* te = s_tok + e * Ttok;
#pragma unroll
            for (int g = 0; g < 2; ++g) {
                if (!valid[g]) continue;
                const f32x4* r = (const f32x4*)(emb + (long)te[tk0[g]] * Dembed + off0[g]);
                f32x4 v0 = r[0], v1 = r[1];
#pragma unroll
                for (int j = 0; j < 4; ++j) { acc[g][j] += w * v0[j]; acc[g][4 + j] += w * v1[j]; }
            }
        }
    }

#pragma unroll
    for (int g = 0; g < 2; ++g) {
        s16x8 o;
#pragma unroll
        for (int j = 0; j < 8; ++j) o[j] = f2b(acc[g][j]);   // invalid groups write zeros
        *(s16x8*)(Ah0 + (long)i * K1 + cg[g]) = o;
    }
}

// ---------------- normalized aggregation (LDS-preloaded lists, 4x unrolled rows) ----------------
template<int NG>
__global__ __launch_bounds__(256)
void k_agg(const short* __restrict__ Hin, short* __restrict__ Hout,
           const float* __restrict__ dinv, const int* __restrict__ rowptr,
           const int* __restrict__ csr, int Wp)
{
    const int i = blockIdx.x;
    const int tid = threadIdx.x;
    __shared__ int   s_idx[64];
    __shared__ float s_w[64];
    const float di = dinv[i];
    const float wself = di * di;
    const long rowi = (long)i * Wp;
    float acc[NG * 8];
#pragma unroll
    for (int gI = 0; gI < NG; ++gI) {
        s16x8 v = *(const s16x8*)(Hin + rowi + gI * 2048 + tid * 8);
#pragma unroll
        for (int j = 0; j < 8; ++j) acc[gI * 8 + j] = wself * b2f(v[j]);
    }
    const int e0 = rowptr[i], e1 = rowptr[i + 1];
    for (int eb = e0; eb < e1; eb += 64) {
        const int cnt = min(64, e1 - eb);
        __syncthreads();
        if (tid < cnt) {
            int s = csr[eb + tid];
            s_idx[tid] = s;
            s_w[tid] = dinv[s] * di;
        }
        __syncthreads();
        int e = 0;
        for (; e + 3 < cnt; e += 4) {          // 4x unroll: 4*NG loads in flight
            const long r0 = (long)s_idx[e] * Wp;
            const long r1 = (long)s_idx[e + 1] * Wp;
            const long r2 = (long)s_idx[e + 2] * Wp;
            const long r3 = (long)s_idx[e + 3] * Wp;
            const float w0 = s_w[e], w1 = s_w[e + 1], w2 = s_w[e + 2], w3 = s_w[e + 3];
            s16x8 v0[NG], v1[NG], v2[NG], v3[NG];
#pragma unroll
            for (int gI = 0; gI < NG; ++gI) {
                v0[gI] = *(const s16x8*)(Hin + r0 + gI * 2048 + tid * 8);
                v1[gI] = *(const s16x8*)(Hin + r1 + gI * 2048 + tid * 8);
                v2[gI] = *(const s16x8*)(Hin + r2 + gI * 2048 + tid * 8);
                v3[gI] = *(const s16x8*)(Hin + r3 + gI * 2048 + tid * 8);
            }
#pragma unroll
            for (int gI = 0; gI < NG; ++gI)
#pragma unroll
                for (int j = 0; j < 8; ++j)
                    acc[gI * 8 + j] += (w0 * b2f(v0[gI][j]) + w1 * b2f(v1[gI][j]))
                                     + (w2 * b2f(v2[gI][j]) + w3 * b2f(v3[gI][j]));
        }
        for (; e < cnt; ++e) {
            const long ra = (long)s_idx[e] * Wp;
            const float wa = s_w[e];
#pragma unroll
            for (int gI = 0; gI < NG; ++gI) {
                s16x8 v = *(const s16x8*)(Hin + ra + gI * 2048 + tid * 8);
#pragma unroll
                for (int j = 0; j < 8; ++j) acc[gI * 8 + j] += wa * b2f(v[j]);
            }
        }
    }
#pragma unroll
    for (int gI = 0; gI < NG; ++gI) {
        s16x8 o;
#pragma unroll
        for (int j = 0; j < 8; ++j) o[j] = f2b(acc[gI * 8 + j]);
        *(s16x8*)(Hout + rowi + gI * 2048 + tid * 8) = o;
    }
}

// ---------------- transpose + fp32->bf16 (vectorized 8B stores) ----------------
__global__ __launch_bounds__(256)
void k_transpose(const float* __restrict__ In, short* __restrict__ Out,
                 int K, int N, int Kp, int Np)
{
    __shared__ float tile[32][33];
    const int k0 = blockIdx.x * 32;
    const int n0 = blockIdx.y * 32;
    const int tid = threadIdx.x;
    const int ln = tid & 31, lk = tid >> 5;   // load: n fast (coalesced)
#pragma unroll
    for (int kk = lk; kk < 32; kk += 8) {
        int k = k0 + kk, n = n0 + ln;
        tile[kk][ln] = (k < K && n < N) ? In[(long)k * N + n] : 0.f;
    }
    __syncthreads();
    const int kq = tid & 7, nn = tid >> 3;    // store: 4 consecutive k per thread
    s16x4 o;
#pragma unroll
    for (int j = 0; j < 4; ++j) o[j] = f2b(tile[kq * 4 + j][nn]);
    *(s16x4*)(&Out[(long)(n0 + nn) * Kp + k0 + kq * 4]) = o;
}

// ---------------- 256^2 pipelined bf16 MFMA GEMM (R14 proven, UNCHANGED) ----------------
__global__ __launch_bounds__(512, 2)
void k_gemm8w(const short* __restrict__ A, const short* __restrict__ Bt,
              short* __restrict__ C, const float* __restrict__ bias,
              int K, int Kloop, int Np, int Nreal, int nbx)
{
    __shared__ short lds[2 * BUFE];   // 128 KiB

    const int tid  = threadIdx.x;
    const int lane = tid & 63;
    const int wid  = tid >> 6;
    const int wm   = wid >> 2;   // 0..1
    const int wn   = wid & 3;    // 0..3

    // T1: XCD-aware block swizzle (gridDim.x % 8 == 0)
    const int cpx = (int)gridDim.x >> 3;
    const int bid = (int)blockIdx.x;
    const int swz = (bid & 7) * cpx + (bid >> 3);
    const int bx = swz % nbx;          // N tile
    const int by = swz / nbx;          // M tile

    // ---- staging (per thread), pre-swizzled global source, linear LDS dest ----
    const int rq = tid >> 3;                                // 0..63 (row within chunk)
    const int kq = ((tid & 7) << 3) ^ ((rq & 7) << 3);      // swizzled k source
    const short* Abase = A  + ((long)by * GBM + rq) * K + kq;
    const short* Bbase = Bt + ((long)bx * GBN + rq) * K + kq;

#define ST2(bb, t2, base, ldoff, c0_, c1_) do { \
    const short* g0_ = (base) + (long)((c0_) * 64) * K + (long)(t2) * GBK; \
    const short* g1_ = (base) + (long)((c1_) * 64) * K + (long)(t2) * GBK; \
    GLL16(g0_, lds + (bb) * BUFE + (ldoff) + (c0_) * 4096 + tid * 8); \
    GLL16(g1_, lds + (bb) * BUFE + (ldoff) + (c1_) * 4096 + tid * 8); \
  } while (0)

    // ---- fragment read addresses (swizzled) ----
    const int fr  = lane & 15;
    const int kb8 = (lane >> 4) << 3;          // 0,8,16,24
    const int xm  = (fr & 7) << 3;
    const int ck0 = kb8 ^ xm;                  // kk=0 column term
    const int ck1 = (32 + kb8) ^ xm;           // kk=32 column term
    const int aoff = (wm * 128 + fr) * 64;     // + m*1024 + ck
    const int boff = ABUF + (wn * 64 + fr) * 64;  // + n*1024 + ck

    f32x4 acc[8][4] = {};
    s16x8 av_a[4], av_b[4], bv1[4], bv3[4];

    const int NT = Kloop >> 6;

    // ---- prologue: stage tile 0 into buf0 ----
    ST2(0, 0, Bbase, ABUF, 0, 1);
    ST2(0, 0, Bbase, ABUF, 2, 3);
    ST2(0, 0, Abase, 0,    0, 2);
    ST2(0, 0, Abase, 0,    1, 3);
    asm volatile("s_waitcnt vmcnt(0)" ::: "memory");
    __builtin_amdgcn_s_barrier();

    int buf = 0;
    for (int t = 0; t < NT; ++t) {
        const short* lb = lds + buf * BUFE;
        const int nb = buf ^ 1;
        const bool pf = (t + 1 < NT);

        // Q1 reads (B kk0 + A m0-3 kk0); issue B01,B23(t+1)
#pragma unroll
        for (int n = 0; n < 4; ++n) bv1[n] = *(const s16x8*)(lb + boff + n * 1024 + ck0);
#pragma unroll
        for (int m = 0; m < 4; ++m) av_a[m] = *(const s16x8*)(lb + aoff + m * 1024 + ck0);
        if (pf) ST2(nb, t + 1, Bbase, ABUF, 0, 1);
        // Q2 reads (A m4-7 kk0)
#pragma unroll
        for (int m = 0; m < 4; ++m) av_b[m] = *(const s16x8*)(lb + aoff + (4 + m) * 1024 + ck0);
        if (pf) ST2(nb, t + 1, Bbase, ABUF, 2, 3);
        // MFMA Q1
        __builtin_amdgcn_s_setprio(1);
#pragma unroll
        for (int m = 0; m < 4; ++m)
#pragma unroll
            for (int n = 0; n < 4; ++n)
                acc[m][n] = __builtin_amdgcn_mfma_f32_16x16x32_bf16(av_a[m], bv1[n], acc[m][n], 0, 0, 0);
        __builtin_amdgcn_s_setprio(0);
        // Q3 reads (B kk32 + A m4-7 kk32); issue A02(t+1)
#pragma unroll
        for (int n = 0; n < 4; ++n) bv3[n] = *(const s16x8*)(lb + boff + n * 1024 + ck1);
#pragma unroll
        for (int m = 0; m < 4; ++m) av_a[m] = *(const s16x8*)(lb + aoff + (4 + m) * 1024 + ck1);
        if (pf) ST2(nb, t + 1, Abase, 0, 0, 2);
        // MFMA Q2
        __builtin_amdgcn_s_setprio(1);
#pragma unroll
        for (int m = 0; m < 4; ++m)
#pragma unroll
            for (int n = 0; n < 4; ++n)
                acc[4 + m][n] = __builtin_amdgcn_mfma_f32_16x16x32_bf16(av_b[m], bv1[n], acc[4 + m][n], 0, 0, 0);
        __builtin_amdgcn_s_setprio(0);
        // Q4 reads (A m0-3 kk32); issue A13(t+1) — 2 quadrants before the drain
#pragma unroll
        for (int m = 0; m < 4; ++m) av_b[m] = *(const s16x8*)(lb + aoff + m * 1024 + ck1);
        if (pf) ST2(nb, t + 1, Abase, 0, 1, 3);
        // MFMA Q3
        __builtin_amdgcn_s_setprio(1);
#pragma unroll
        for (int m = 0; m < 4; ++m)
#pragma unroll
            for (int n = 0; n < 4; ++n)
                acc[4 + m][n] = __builtin_amdgcn_mfma_f32_16x16x32_bf16(av_a[m], bv3[n], acc[4 + m][n], 0, 0, 0);
        __builtin_amdgcn_s_setprio(0);
        // MFMA Q4
        __builtin_amdgcn_s_setprio(1);
#pragma unroll
        for (int m = 0; m < 4; ++m)
#pragma unroll
            for (int n = 0; n < 4; ++n)
                acc[m][n] = __builtin_amdgcn_mfma_f32_16x16x32_bf16(av_b[m], bv3[n], acc[m][n], 0, 0, 0);
        __builtin_amdgcn_s_setprio(0);

        // boundary: drain (all issues >= 2 quadrants old) + single barrier
        asm volatile("s_waitcnt vmcnt(0)" ::: "memory");
        __builtin_amdgcn_s_barrier();
        buf = nb;
    }

    // ---- epilogue: bias + leaky + bf16 store, n-INNERMOST for line coalescing ----
    const int rr = (lane >> 4) << 2;
    long colv[4];
    float bb[4];
#pragma unroll
    for (int n = 0; n < 4; ++n) {
        colv[n] = (long)bx * GBN + wn * 64 + n * 16 + fr;
        bb[n] = (colv[n] < Nreal) ? bias[colv[n]] : 0.f;
    }
#pragma unroll
    for (int m = 0; m < 8; ++m) {
#pragma unroll
        for (int j = 0; j < 4; ++j) {
            const long rowoff = ((long)by * GBM + wm * 128 + m * 16 + rr + j) * Np;
#pragma unroll
            for (int n = 0; n < 4; ++n) {
                float v = acc[m][n][j] + bb[n];
                v = LRELU(v);
                C[rowoff + colv[n]] = f2b(v);
            }
        }
    }
#undef ST2
}

// ---------------- batch boundaries ----------------
__global__ void k_bptr(const int* __restrict__ batch, int* __restrict__ bptr) {
    int i = blockIdx.x * 256 + threadIdx.x;
    if (i >= Nn) return;
    int b = batch[i];
    int pb = (i == 0) ? -1 : batch[i - 1];
    for (int bb = pb + 1; bb <= b; ++bb) bptr[bb] = i;
    if (i == Nn - 1)
        for (int bb = b + 1; bb <= Bb; ++bb) bptr[bb] = Nn;
}

// ---------------- global max pool, row-split 4x: gpart[rc][b][col] ----------------
__global__ __launch_bounds__(256)
void k_pool_part(const short* __restrict__ h2, const int* __restrict__ bptr,
                 float* __restrict__ gpart, int Wp) {
    const int c8 = blockIdx.x * 256 + threadIdx.x;   // group of 8 cols
    const int b = blockIdx.y;
    const int rc = blockIdx.z;
    const short* base = h2 + (long)c8 * 8;
    float mx[8];
#pragma unroll
    for (int j = 0; j < 8; ++j) mx[j] = -INFINITY;
    const int i0 = bptr[b], i1 = bptr[b + 1];
    const int len = i1 - i0;
    const int ca = i0 + (len * rc) / 4;
    const int cb = i0 + (len * (rc + 1)) / 4;
    for (int i = ca; i < cb; ++i) {
        s16x8 v = *(const s16x8*)(base + (long)i * Wp);
#pragma unroll
        for (int j = 0; j < 8; ++j) mx[j] = fmaxf(mx[j], b2f(v[j]));
    }
    float* o = gpart + ((long)rc * Bb + b) * Wp + c8 * 8;
#pragma unroll
    for (int j = 0; j < 8; ++j) o[j] = mx[j];
}

__global__ __launch_bounds__(256)
void k_pool_red(const float* __restrict__ gpart, float* __restrict__ g) {
    int idx = blockIdx.x * 256 + threadIdx.x;   // over Bb*K2
    if (idx >= Bb * K2) return;
    float m = gpart[idx];
#pragma unroll
    for (int rc = 1; rc < 4; ++rc)
        m = fmaxf(m, gpart[(long)rc * Bb * K2 + idx]);
    g[idx] = m;
}

// ---------------- linear1 split-K ----------------
__global__ __launch_bounds__(256)
void k_lin1_part(const float* __restrict__ g, const float* __restrict__ Wl1,
                 float* __restrict__ part) {
    __shared__ float gs[64][65];
    __shared__ float Ws[64][64];
    const int tid = threadIdx.x;
    const int jc = blockIdx.x * 64;
    const int k0 = blockIdx.y * LCHUNK;
    const int k1 = min(6000, k0 + LCHUNK);
    const int r = tid & 63;
    const int jb = (tid >> 6) * 16;
    float acc[16] = {};
    for (int kc = k0; kc < k1; kc += 64) {
#pragma unroll
        for (int p = 0; p < 16; ++p) {
            int el = p * 256 + tid;
            int rr = el >> 6, kk = el & 63;
            gs[rr][kk] = (kc + kk < k1) ? g[rr * K2 + kc + kk] : 0.f;
            Ws[rr][kk] = (kc + rr < k1 && jc + kk < 3000)
                         ? Wl1[(long)(kc + rr) * 3000 + jc + kk] : 0.f;
        }
        __syncthreads();
#pragma unroll
        for (int k = 0; k < 64; ++k) {
            float a = gs[r][k];
#pragma unroll
            for (int jj = 0; jj < 16; ++jj)
                acc[jj] += a * Ws[k][jb + jj];
        }
        __syncthreads();
    }
    float* prow = part + ((long)blockIdx.y * 64 + r) * L1p + jc + jb;
#pragma unroll
    for (int jj = 0; jj < 16; ++jj) prow[jj] = acc[jj];
}

__global__ __launch_bounds__(256)
void k_lin1_red(const float* __restrict__ part, const float* __restrict__ bl1,
                float* __restrict__ g1) {
    int idx = blockIdx.x * 256 + threadIdx.x;
    if (idx >= 64 * 3000) return;
    int r = idx / 3000;
    int c = idx - r * 3000;
    float s = bl1[c];
#pragma unroll
    for (int p = 0; p < NCH; ++p)
        s += part[((long)p * 64 + r) * L1p + c];
    g1[r * L1p + c] = LRELU(s);
}

// ---------------- linear2 ----------------
__global__ __launch_bounds__(256)
void k_lin2(const float* __restrict__ g1, const float* __restrict__ Wl2,
            const float* __restrict__ bl2, float* __restrict__ out) {
    const int r = blockIdx.x;
    const int tid = threadIdx.x;
    float a0 = 0, a1 = 0, a2 = 0, a3 = 0;
    for (int k = tid; k < 3000; k += 256) {
        float gv = g1[r * L1p + k];
        const float* w = Wl2 + (long)k * 4;
        a0 += gv * w[0]; a1 += gv * w[1]; a2 += gv * w[2]; a3 += gv * w[3];
    }
    __shared__ float red[256][4];
    red[tid][0] = a0; red[tid][1] = a1; red[tid][2] = a2; red[tid][3] = a3;
    __syncthreads();
    for (int s = 128; s > 0; s >>= 1) {
        if (tid < s) {
            red[tid][0] += red[tid + s][0]; red[tid][1] += red[tid + s][1];
            red[tid][2] += red[tid + s][2]; red[tid][3] += red[tid + s][3];
        }
        __syncthreads();
    }
    if (tid < 4) {
        float v = red[0][tid] + bl2[tid];
        out[r * 4 + tid] = LRELU(v);
    }
}

// ---------------- launch ----------------
extern "C" void kernel_launch(void* const* d_in, const int* in_sizes, int n_in,
                              void* d_out, int out_size, void* d_ws, size_t ws_size,
                              hipStream_t stream)
{
    const int*   x     = (const int*)d_in[0];
    const int*   ei    = (const int*)d_in[1];
    const int*   batch = (const int*)d_in[2];
    const float* emb   = (const float*)d_in[3];
    const float* W1    = (const float*)d_in[4];
    const float* b1    = (const float*)d_in[5];
    const float* W2    = (const float*)d_in[6];
    const float* b2    = (const float*)d_in[7];
    const float* Wl1   = (const float*)d_in[8];
    const float* bl1   = (const float*)d_in[9];
    const float* Wl2   = (const float*)d_in[10];
    const float* bl2   = (const float*)d_in[11];
    float* out = (float*)d_out;

    const int* esrc = ei;
    const int* edst = ei + Ee;

    const size_t MiB = 1ull << 20;
    char* W = (char*)d_ws;
    short* Ah0b = (short*)(W + 64 * MiB);   // [8192,4096] bf16, 64 MiB
    short* W2t  = (short*)(W + 96 * MiB);   // [6144,6144] bf16, 72 MiB (after GEMM1)
    short* W1t  = (short*)(W + 128 * MiB);  // [6144,4096] bf16, 48 MiB
    short* h1b  = (short*)(W + 176 * MiB);  // [8192,6144] bf16, 96 MiB
    short* Ah1b = (short*)(W + 0);          // [8192,6144] bf16, 96 MiB (after GEMM1)
    short* h2b  = h1b;                      // reuse
    float* part = (float*)(W + 0);          // [24][64][3072] f32 (after pool)
    float* gpart = (float*)(W + 128 * MiB); // [4][64][6144] f32, 6 MB (W1t dead after GEMM1)
    char* S = W + 272 * MiB;
    int*   indeg  = (int*)(S);                 // 32 KB
    int*   fillc  = (int*)(S + 32 * 1024);     // 32 KB (adjacent -> single memset)
    int*   rowptr = (int*)(S + 64 * 1024);
    float* dinv   = (float*)(S + 96 * 1024);
    int*   csr    = (int*)(S + 128 * 1024);
    int*   bptr   = (int*)(S + 256 * 1024);
    float* g      = (float*)(S + 320 * 1024);
    float* g1     = (float*)(S + 320 * 1024 + 2 * MiB);

    hipMemsetAsync(indeg, 0, 64 * 1024, stream);   // indeg + fillc in one shot

    k_deg<<<(Ee + 255) / 256, 256, 0, stream>>>(edst, indeg);
    k_scan<<<1, 1024, 0, stream>>>(indeg, rowptr, dinv, Nn);
    k_fill<<<(Ee + 255) / 256, 256, 0, stream>>>(esrc, edst, rowptr, fillc, csr);

    const int nbx = K2 / GBN;               // 24
    const int nwg = nbx * (Mp / GBM);       // 24*32 = 768, % 8 == 0

    k_gagg<<<Nn, 256, 0, stream>>>(x, emb, dinv, rowptr, csr, Ah0b);
    k_transpose<<<dim3(K1 / 32, K2 / 32), 256, 0, stream>>>(W1, W1t, 4000, 6000, K1, K2);
    k_gemm8w<<<nwg, 512, 0, stream>>>(Ah0b, W1t, h1b, b1, K1, K1L, K2, 6000, nbx);

    k_transpose<<<dim3(K2 / 32, K2 / 32), 256, 0, stream>>>(W2, W2t, 6000, 6000, K2, K2);
    k_agg<3><<<Nn, 256, 0, stream>>>(h1b, Ah1b, dinv, rowptr, csr, K2);
    k_gemm8w<<<nwg, 512, 0, stream>>>(Ah1b, W2t, h2b, b2, K2, K2L, K2, 6000, nbx);

    k_bptr<<<(Nn + 255) / 256, 256, 0, stream>>>(batch, bptr);
    k_pool_part<<<dim3(K2 / 2048, Bb, 4), 256, 0, stream>>>(h2b, bptr, gpart, K2);
    k_pool_red<<<(Bb * K2 + 255) / 256, 256, 0, stream>>>(gpart, g);
    k_lin1_part<<<dim3(L1p / 64, NCH), 256, 0, stream>>>(g, Wl1, part);
    k_lin1_red<<<(64 * 3000 + 255) / 256, 256, 0, stream>>>(part, bl1, g1);
    k_lin2<<<Bb, 256, 0, stream>>>(g1, Wl2, bl2, out);
}

// Round 16
// 1226.058 us; speedup vs baseline: 1.0984x; 1.0011x over previous
//
#include <hip/hip_runtime.h>
#include <hip/hip_bf16.h>

// ---------------- problem constants ----------------
#define Nn 8000      // nodes
#define Ee 32000     // edges
#define Bb 64        // graphs
#define Dembed 200
#define Ttok 20
#define Mp 8192      // padded node count
#define K1 4096      // padded 4000 (layer-1 in dim)
#define K1L 4032     // K-loop trim: first mult of 64 >= 4000
#define K2 6144      // padded 6000 (layer-1/2 out dim)
#define K2L 6016     // K-loop trim: first mult of 64 >= 6000
#define L1p 3072     // padded 3000
#define LCHUNK 256   // split-K chunk for lin1
#define NCH 24       // ceil(6000/256)

// GEMM tile geometry (256^2, 8 waves x 128x64, single-barrier tile loop) — R14 proven
#define GBM 256
#define GBN 256
#define GBK 64
#define ABUF (GBM * GBK)          // 16384 els (A region per buffer)
#define BUFE (2 * ABUF)           // 32768 els per buffer (A+B)

#define LRELU(v) ((v) > 0.f ? (v) : 0.01f * (v))

typedef __attribute__((ext_vector_type(4))) float f32x4;
typedef __attribute__((ext_vector_type(8))) short s16x8;
typedef __attribute__((ext_vector_type(4))) short s16x4;

#define GLL16(gp, lp) __builtin_amdgcn_global_load_lds( \
    (const __attribute__((address_space(1))) void*)(gp), \
    (__attribute__((address_space(3))) void*)(lp), 16, 0, 0)

__device__ __forceinline__ float b2f(short s) {
    union { unsigned u; float f; } c;
    c.u = ((unsigned)(unsigned short)s) << 16;
    return c.f;
}
__device__ __forceinline__ short f2b(float f) {
    __hip_bfloat16 h = __float2bfloat16(f);  // RNE
    return __builtin_bit_cast(short, h);
}

// ---------------- merged preamble: degree count (blocks 0..124) + batch boundaries (125..156) ----------------
__global__ __launch_bounds__(256)
void k_pre(const int* __restrict__ dst, int* __restrict__ indeg,
           const int* __restrict__ batch, int* __restrict__ bptr) {
    const int bid = blockIdx.x;
    if (bid < 125) {
        int e = bid * 256 + threadIdx.x;
        if (e < Ee) atomicAdd(&indeg[dst[e]], 1);
    } else {
        int i = (bid - 125) * 256 + threadIdx.x;
        if (i >= Nn) return;
        int b = batch[i];
        int pb = (i == 0) ? -1 : batch[i - 1];
        for (int bb = pb + 1; bb <= b; ++bb) bptr[bb] = i;
        if (i == Nn - 1)
            for (int bb = b + 1; bb <= Bb; ++bb) bptr[bb] = Nn;
    }
}

// single-block exclusive scan of indeg -> rowptr, plus dinv (fused)
__global__ __launch_bounds__(1024)
void k_scan(const int* __restrict__ indeg, int* __restrict__ rowptr,
            float* __restrict__ dinv, int n)
{
    __shared__ int sums[1024];
    const int t = threadIdx.x;
    const int base = t * 8;
    int loc[8];
    int s = 0;
#pragma unroll
    for (int j = 0; j < 8; ++j) {
        int v = (base + j < n) ? indeg[base + j] : 0;
        loc[j] = s; s += v;
    }
    sums[t] = s;
    __syncthreads();
    for (int off = 1; off < 1024; off <<= 1) {
        int v = sums[t];
        int add = (t >= off) ? sums[t - off] : 0;
        __syncthreads();
        sums[t] = v + add;
        __syncthreads();
    }
    const int prev = (t == 0) ? 0 : sums[t - 1];
#pragma unroll
    for (int j = 0; j < 8; ++j)
        if (base + j < n) {
            rowptr[base + j] = prev + loc[j];
            dinv[base + j] = rsqrtf((float)indeg[base + j] + 1.0f);
        }
    if (t == 1023) rowptr[n] = sums[1023];
}

__global__ void k_fill(const int* __restrict__ src, const int* __restrict__ dst,
                       const int* __restrict__ rowptr, int* __restrict__ fillc,
                       int* __restrict__ csr) {
    int e = blockIdx.x * 256 + threadIdx.x;
    if (e < Ee) {
        int d = dst[e];
        int pos = rowptr[d] + atomicAdd(&fillc[d], 1);
        csr[pos] = src[e];
    }
}

// ---------------- fused gather+agg1 (4x neighbor unroll) ----------------
// Ah0[i] = dinv_i^2*emb(x_i) + sum_s w_si*emb(x_s); emb 4MB L2-resident; fp32 accum.
__global__ __launch_bounds__(256)
void k_gagg(const int* __restrict__ x, const float* __restrict__ emb,
            const float* __restrict__ dinv, const int* __restrict__ rowptr,
            const int* __restrict__ csr, short* __restrict__ Ah0)
{
    const int i = blockIdx.x;
    const int tid = threadIdx.x;
    __shared__ float s_w[64];
    __shared__ int s_tok[64 * Ttok];
    __shared__ int s_tok0[Ttok];

    int cg[2], tk0[2], off0[2];
    bool valid[2];
#pragma unroll
    for (int g = 0; g < 2; ++g) {
        cg[g] = tid * 8 + g * 2048;
        valid[g] = (cg[g] < Ttok * Dembed);   // < 4000
        tk0[g] = cg[g] / Dembed;
        off0[g] = cg[g] - tk0[g] * Dembed;    // multiple of 8; 200-off0 >= 8 always
    }

    const float di = dinv[i];
    const float wself = di * di;

    if (tid < Ttok) s_tok0[tid] = x[i * Ttok + tid];
    __syncthreads();

    float acc[2][8] = {};
#pragma unroll
    for (int g = 0; g < 2; ++g) {
        if (!valid[g]) continue;
        const f32x4* r = (const f32x4*)(emb + (long)s_tok0[tk0[g]] * Dembed + off0[g]);
        f32x4 v0 = r[0], v1 = r[1];
#pragma unroll
        for (int j = 0; j < 4; ++j) { acc[g][j] = wself * v0[j]; acc[g][4 + j] = wself * v1[j]; }
    }

    const int e0 = rowptr[i], e1 = rowptr[i + 1];
    for (int eb = e0; eb < e1; eb += 64) {
        const int cnt = min(64, e1 - eb);
        __syncthreads();
        if (tid < cnt) {
            int s = csr[eb + tid];
            s_w[tid] = dinv[s] * di;
        }
        __syncthreads();
        for (int f = tid; f < cnt * Ttok; f += 256) {
            int e = f / Ttok;
            int tk = f - e * Ttok;
            s_tok[f] = x[(long)csr[eb + e] * Ttok + tk];
        }
        __syncthreads();
        int e = 0;
        for (; e + 3 < cnt; e += 4) {      // 4x unroll: 8 f32x4 loads in flight per group
            const float w0 = s_w[e], w1 = s_w[e + 1], w2 = s_w[e + 2], w3 = s_w[e + 3];
            const int* t0 = s_tok + e * Ttok;
            const int* t1 = t0 + Ttok;
            const int* t2 = t1 + Ttok;
            const int* t3 = t2 + Ttok;
#pragma unroll
            for (int g = 0; g < 2; ++g) {
                if (!valid[g]) continue;
                const f32x4* r0 = (const f32x4*)(emb + (long)t0[tk0[g]] * Dembed + off0[g]);
                const f32x4* r1 = (const f32x4*)(emb + (long)t1[tk0[g]] * Dembed + off0[g]);
                const f32x4* r2 = (const f32x4*)(emb + (long)t2[tk0[g]] * Dembed + off0[g]);
                const f32x4* r3 = (const f32x4*)(emb + (long)t3[tk0[g]] * Dembed + off0[g]);
                f32x4 a0 = r0[0], a1 = r0[1], b0 = r1[0], b1 = r1[1];
                f32x4 c0 = r2[0], c1 = r2[1], d0 = r3[0], d1 = r3[1];
#pragma unroll
                for (int j = 0; j < 4; ++j) {
                    acc[g][j]     += (w0 * a0[j] + w1 * b0[j]) + (w2 * c0[j] + w3 * d0[j]);
                    acc[g][4 + j] += (w0 * a1[j] + w1 * b1[j]) + (w2 * c1[j] + w3 * d1[j]);
                }
            }
        }
        for (; e < cnt; ++e) {
            const float w = s_w[e];
            const int* te = s_tok + e * Ttok;
#pragma unroll
            for (int g = 0; g < 2; ++g) {
                if (!valid[g]) continue;
                const f32x4* r = (const f32x4*)(emb + (long)te[tk0[g]] * Dembed + off0[g]);
                f32x4 v0 = r[0], v1 = r[1];
#pragma unroll
                for (int j = 0; j < 4; ++j) { acc[g][j] += w * v0[j]; acc[g][4 + j] += w * v1[j]; }
            }
        }
    }

#pragma unroll
    for (int g = 0; g < 2; ++g) {
        s16x8 o;
#pragma unroll
        for (int j = 0; j < 8; ++j) o[j] = f2b(acc[g][j]);   // invalid groups write zeros
        *(s16x8*)(Ah0 + (long)i * K1 + cg[g]) = o;
    }
}

// ---------------- normalized aggregation (LDS-preloaded lists, 4x unrolled rows) ----------------
template<int NG>
__global__ __launch_bounds__(256)
void k_agg(const short* __restrict__ Hin, short* __restrict__ Hout,
           const float* __restrict__ dinv, const int* __restrict__ rowptr,
           const int* __restrict__ csr, int Wp)
{
    const int i = blockIdx.x;
    const int tid = threadIdx.x;
    __shared__ int   s_idx[64];
    __shared__ float s_w[64];
    const float di = dinv[i];
    const float wself = di * di;
    const long rowi = (long)i * Wp;
    float acc[NG * 8];
#pragma unroll
    for (int gI = 0; gI < NG; ++gI) {
        s16x8 v = *(const s16x8*)(Hin + rowi + gI * 2048 + tid * 8);
#pragma unroll
        for (int j = 0; j < 8; ++j) acc[gI * 8 + j] = wself * b2f(v[j]);
    }
    const int e0 = rowptr[i], e1 = rowptr[i + 1];
    for (int eb = e0; eb < e1; eb += 64) {
        const int cnt = min(64, e1 - eb);
        __syncthreads();
        if (tid < cnt) {
            int s = csr[eb + tid];
            s_idx[tid] = s;
            s_w[tid] = dinv[s] * di;
        }
        __syncthreads();
        int e = 0;
        for (; e + 3 < cnt; e += 4) {          // 4x unroll: 4*NG loads in flight
            const long r0 = (long)s_idx[e] * Wp;
            const long r1 = (long)s_idx[e + 1] * Wp;
            const long r2 = (long)s_idx[e + 2] * Wp;
            const long r3 = (long)s_idx[e + 3] * Wp;
            const float w0 = s_w[e], w1 = s_w[e + 1], w2 = s_w[e + 2], w3 = s_w[e + 3];
            s16x8 v0[NG], v1[NG], v2[NG], v3[NG];
#pragma unroll
            for (int gI = 0; gI < NG; ++gI) {
                v0[gI] = *(const s16x8*)(Hin + r0 + gI * 2048 + tid * 8);
                v1[gI] = *(const s16x8*)(Hin + r1 + gI * 2048 + tid * 8);
                v2[gI] = *(const s16x8*)(Hin + r2 + gI * 2048 + tid * 8);
                v3[gI] = *(const s16x8*)(Hin + r3 + gI * 2048 + tid * 8);
            }
#pragma unroll
            for (int gI = 0; gI < NG; ++gI)
#pragma unroll
                for (int j = 0; j < 8; ++j)
                    acc[gI * 8 + j] += (w0 * b2f(v0[gI][j]) + w1 * b2f(v1[gI][j]))
                                     + (w2 * b2f(v2[gI][j]) + w3 * b2f(v3[gI][j]));
        }
        for (; e < cnt; ++e) {
            const long ra = (long)s_idx[e] * Wp;
            const float wa = s_w[e];
#pragma unroll
            for (int gI = 0; gI < NG; ++gI) {
                s16x8 v = *(const s16x8*)(Hin + ra + gI * 2048 + tid * 8);
#pragma unroll
                for (int j = 0; j < 8; ++j) acc[gI * 8 + j] += wa * b2f(v[j]);
            }
        }
    }
#pragma unroll
    for (int gI = 0; gI < NG; ++gI) {
        s16x8 o;
#pragma unroll
        for (int j = 0; j < 8; ++j) o[j] = f2b(acc[gI * 8 + j]);
        *(s16x8*)(Hout + rowi + gI * 2048 + tid * 8) = o;
    }
}

// ---------------- transpose + fp32->bf16 (vectorized 8B stores) ----------------
__global__ __launch_bounds__(256)
void k_transpose(const float* __restrict__ In, short* __restrict__ Out,
                 int K, int N, int Kp, int Np)
{
    __shared__ float tile[32][33];
    const int k0 = blockIdx.x * 32;
    const int n0 = blockIdx.y * 32;
    const int tid = threadIdx.x;
    const int ln = tid & 31, lk = tid >> 5;   // load: n fast (coalesced)
#pragma unroll
    for (int kk = lk; kk < 32; kk += 8) {
        int k = k0 + kk, n = n0 + ln;
        tile[kk][ln] = (k < K && n < N) ? In[(long)k * N + n] : 0.f;
    }
    __syncthreads();
    const int kq = tid & 7, nn = tid >> 3;    // store: 4 consecutive k per thread
    s16x4 o;
#pragma unroll
    for (int j = 0; j < 4; ++j) o[j] = f2b(tile[kq * 4 + j][nn]);
    *(s16x4*)(&Out[(long)(n0 + nn) * Kp + k0 + kq * 4]) = o;
}

// ---------------- 256^2 pipelined bf16 MFMA GEMM (R14 proven, UNCHANGED) ----------------
__global__ __launch_bounds__(512, 2)
void k_gemm8w(const short* __restrict__ A, const short* __restrict__ Bt,
              short* __restrict__ C, const float* __restrict__ bias,
              int K, int Kloop, int Np, int Nreal, int nbx)
{
    __shared__ short lds[2 * BUFE];   // 128 KiB

    const int tid  = threadIdx.x;
    const int lane = tid & 63;
    const int wid  = tid >> 6;
    const int wm   = wid >> 2;   // 0..1
    const int wn   = wid & 3;    // 0..3

    // T1: XCD-aware block swizzle (gridDim.x % 8 == 0)
    const int cpx = (int)gridDim.x >> 3;
    const int bid = (int)blockIdx.x;
    const int swz = (bid & 7) * cpx + (bid >> 3);
    const int bx = swz % nbx;          // N tile
    const int by = swz / nbx;          // M tile

    // ---- staging (per thread), pre-swizzled global source, linear LDS dest ----
    const int rq = tid >> 3;                                // 0..63 (row within chunk)
    const int kq = ((tid & 7) << 3) ^ ((rq & 7) << 3);      // swizzled k source
    const short* Abase = A  + ((long)by * GBM + rq) * K + kq;
    const short* Bbase = Bt + ((long)bx * GBN + rq) * K + kq;

#define ST2(bb, t2, base, ldoff, c0_, c1_) do { \
    const short* g0_ = (base) + (long)((c0_) * 64) * K + (long)(t2) * GBK; \
    const short* g1_ = (base) + (long)((c1_) * 64) * K + (long)(t2) * GBK; \
    GLL16(g0_, lds + (bb) * BUFE + (ldoff) + (c0_) * 4096 + tid * 8); \
    GLL16(g1_, lds + (bb) * BUFE + (ldoff) + (c1_) * 4096 + tid * 8); \
  } while (0)

    // ---- fragment read addresses (swizzled) ----
    const int fr  = lane & 15;
    const int kb8 = (lane >> 4) << 3;          // 0,8,16,24
    const int xm  = (fr & 7) << 3;
    const int ck0 = kb8 ^ xm;                  // kk=0 column term
    const int ck1 = (32 + kb8) ^ xm;           // kk=32 column term
    const int aoff = (wm * 128 + fr) * 64;     // + m*1024 + ck
    const int boff = ABUF + (wn * 64 + fr) * 64;  // + n*1024 + ck

    f32x4 acc[8][4] = {};
    s16x8 av_a[4], av_b[4], bv1[4], bv3[4];

    const int NT = Kloop >> 6;

    // ---- prologue: stage tile 0 into buf0 ----
    ST2(0, 0, Bbase, ABUF, 0, 1);
    ST2(0, 0, Bbase, ABUF, 2, 3);
    ST2(0, 0, Abase, 0,    0, 2);
    ST2(0, 0, Abase, 0,    1, 3);
    asm volatile("s_waitcnt vmcnt(0)" ::: "memory");
    __builtin_amdgcn_s_barrier();

    int buf = 0;
    for (int t = 0; t < NT; ++t) {
        const short* lb = lds + buf * BUFE;
        const int nb = buf ^ 1;
        const bool pf = (t + 1 < NT);

        // Q1 reads (B kk0 + A m0-3 kk0); issue B01(t+1)
#pragma unroll
        for (int n = 0; n < 4; ++n) bv1[n] = *(const s16x8*)(lb + boff + n * 1024 + ck0);
#pragma unroll
        for (int m = 0; m < 4; ++m) av_a[m] = *(const s16x8*)(lb + aoff + m * 1024 + ck0);
        if (pf) ST2(nb, t + 1, Bbase, ABUF, 0, 1);
        // Q2 reads (A m4-7 kk0); issue B23(t+1)
#pragma unroll
        for (int m = 0; m < 4; ++m) av_b[m] = *(const s16x8*)(lb + aoff + (4 + m) * 1024 + ck0);
        if (pf) ST2(nb, t + 1, Bbase, ABUF, 2, 3);
        // MFMA Q1
        __builtin_amdgcn_s_setprio(1);
#pragma unroll
        for (int m = 0; m < 4; ++m)
#pragma unroll
            for (int n = 0; n < 4; ++n)
                acc[m][n] = __builtin_amdgcn_mfma_f32_16x16x32_bf16(av_a[m], bv1[n], acc[m][n], 0, 0, 0);
        __builtin_amdgcn_s_setprio(0);
        // Q3 reads (B kk32 + A m4-7 kk32); issue A02(t+1)
#pragma unroll
        for (int n = 0; n < 4; ++n) bv3[n] = *(const s16x8*)(lb + boff + n * 1024 + ck1);
#pragma unroll
        for (int m = 0; m < 4; ++m) av_a[m] = *(const s16x8*)(lb + aoff + (4 + m) * 1024 + ck1);
        if (pf) ST2(nb, t + 1, Abase, 0, 0, 2);
        // MFMA Q2
        __builtin_amdgcn_s_setprio(1);
#pragma unroll
        for (int m = 0; m < 4; ++m)
#pragma unroll
            for (int n = 0; n < 4; ++n)
                acc[4 + m][n] = __builtin_amdgcn_mfma_f32_16x16x32_bf16(av_b[m], bv1[n], acc[4 + m][n], 0, 0, 0);
        __builtin_amdgcn_s_setprio(0);
        // Q4 reads (A m0-3 kk32); issue A13(t+1) — 2 quadrants before the drain
#pragma unroll
        for (int m = 0; m < 4; ++m) av_b[m] = *(const s16x8*)(lb + aoff + m * 1024 + ck1);
        if (pf) ST2(nb, t + 1, Abase, 0, 1, 3);
        // MFMA Q3
        __builtin_amdgcn_s_setprio(1);
#pragma unroll
        for (int m = 0; m < 4; ++m)
#pragma unroll
            for (int n = 0; n < 4; ++n)
                acc[4 + m][n] = __builtin_amdgcn_mfma_f32_16x16x32_bf16(av_a[m], bv3[n], acc[4 + m][n], 0, 0, 0);
        __builtin_amdgcn_s_setprio(0);
        // MFMA Q4
        __builtin_amdgcn_s_setprio(1);
#pragma unroll
        for (int m = 0; m < 4; ++m)
#pragma unroll
            for (int n = 0; n < 4; ++n)
                acc[m][n] = __builtin_amdgcn_mfma_f32_16x16x32_bf16(av_b[m], bv3[n], acc[m][n], 0, 0, 0);
        __builtin_amdgcn_s_setprio(0);

        // boundary: drain (all issues >= 2 quadrants old) + single barrier
        asm volatile("s_waitcnt vmcnt(0)" ::: "memory");
        __builtin_amdgcn_s_barrier();
        buf = nb;
    }

    // ---- epilogue: bias + leaky + bf16 store, n-INNERMOST for line coalescing ----
    const int rr = (lane >> 4) << 2;
    long colv[4];
    float bb[4];
#pragma unroll
    for (int n = 0; n < 4; ++n) {
        colv[n] = (long)bx * GBN + wn * 64 + n * 16 + fr;
        bb[n] = (colv[n] < Nreal) ? bias[colv[n]] : 0.f;
    }
#pragma unroll
    for (int m = 0; m < 8; ++m) {
#pragma unroll
        for (int j = 0; j < 4; ++j) {
            const long rowoff = ((long)by * GBM + wm * 128 + m * 16 + rr + j) * Np;
#pragma unroll
            for (int n = 0; n < 4; ++n) {
                float v = acc[m][n][j] + bb[n];
                v = LRELU(v);
                C[rowoff + colv[n]] = f2b(v);
            }
        }
    }
#undef ST2
}

// ---------------- global max pool, row-split 4x: gpart[rc][b][col] ----------------
__global__ __launch_bounds__(256)
void k_pool_part(const short* __restrict__ h2, const int* __restrict__ bptr,
                 float* __restrict__ gpart, int Wp) {
    const int c8 = blockIdx.x * 256 + threadIdx.x;   // group of 8 cols
    const int b = blockIdx.y;
    const int rc = blockIdx.z;
    const short* base = h2 + (long)c8 * 8;
    float mx[8];
#pragma unroll
    for (int j = 0; j < 8; ++j) mx[j] = -INFINITY;
    const int i0 = bptr[b], i1 = bptr[b + 1];
    const int len = i1 - i0;
    const int ca = i0 + (len * rc) / 4;
    const int cb = i0 + (len * (rc + 1)) / 4;
    for (int i = ca; i < cb; ++i) {
        s16x8 v = *(const s16x8*)(base + (long)i * Wp);
#pragma unroll
        for (int j = 0; j < 8; ++j) mx[j] = fmaxf(mx[j], b2f(v[j]));
    }
    float* o = gpart + ((long)rc * Bb + b) * Wp + c8 * 8;
#pragma unroll
    for (int j = 0; j < 8; ++j) o[j] = mx[j];
}

__global__ __launch_bounds__(256)
void k_pool_red(const float* __restrict__ gpart, float* __restrict__ g) {
    int idx = blockIdx.x * 256 + threadIdx.x;   // over Bb*K2
    if (idx >= Bb * K2) return;
    float m = gpart[idx];
#pragma unroll
    for (int rc = 1; rc < 4; ++rc)
        m = fmaxf(m, gpart[(long)rc * Bb * K2 + idx]);
    g[idx] = m;
}

// ---------------- linear1 split-K ----------------
__global__ __launch_bounds__(256)
void k_lin1_part(const float* __restrict__ g, const float* __restrict__ Wl1,
                 float* __restrict__ part) {
    __shared__ float gs[64][65];
    __shared__ float Ws[64][64];
    const int tid = threadIdx.x;
    const int jc = blockIdx.x * 64;
    const int k0 = blockIdx.y * LCHUNK;
    const int k1 = min(6000, k0 + LCHUNK);
    const int r = tid & 63;
    const int jb = (tid >> 6) * 16;
    float acc[16] = {};
    for (int kc = k0; kc < k1; kc += 64) {
#pragma unroll
        for (int p = 0; p < 16; ++p) {
            int el = p * 256 + tid;
            int rr = el >> 6, kk = el & 63;
            gs[rr][kk] = (kc + kk < k1) ? g[rr * K2 + kc + kk] : 0.f;
            Ws[rr][kk] = (kc + rr < k1 && jc + kk < 3000)
                         ? Wl1[(long)(kc + rr) * 3000 + jc + kk] : 0.f;
        }
        __syncthreads();
#pragma unroll
        for (int k = 0; k < 64; ++k) {
            float a = gs[r][k];
#pragma unroll
            for (int jj = 0; jj < 16; ++jj)
                acc[jj] += a * Ws[k][jb + jj];
        }
        __syncthreads();
    }
    float* prow = part + ((long)blockIdx.y * 64 + r) * L1p + jc + jb;
#pragma unroll
    for (int jj = 0; jj < 16; ++jj) prow[jj] = acc[jj];
}

__global__ __launch_bounds__(256)
void k_lin1_red(const float* __restrict__ part, const float* __restrict__ bl1,
                float* __restrict__ g1) {
    int idx = blockIdx.x * 256 + threadIdx.x;
    if (idx >= 64 * 3000) return;
    int r = idx / 3000;
    int c = idx - r * 3000;
    float s = bl1[c];
#pragma unroll
    for (int p = 0; p < NCH; ++p)
        s += part[((long)p * 64 + r) * L1p + c];
    g1[r * L1p + c] = LRELU(s);
}

// ---------------- linear2 ----------------
__global__ __launch_bounds__(256)
void k_lin2(const float* __restrict__ g1, const float* __restrict__ Wl2,
            const float* __restrict__ bl2, float* __restrict__ out) {
    const int r = blockIdx.x;
    const int tid = threadIdx.x;
    float a0 = 0, a1 = 0, a2 = 0, a3 = 0;
    for (int k = tid; k < 3000; k += 256) {
        float gv = g1[r * L1p + k];
        const float* w = Wl2 + (long)k * 4;
        a0 += gv * w[0]; a1 += gv * w[1]; a2 += gv * w[2]; a3 += gv * w[3];
    }
    __shared__ float red[256][4];
    red[tid][0] = a0; red[tid][1] = a1; red[tid][2] = a2; red[tid][3] = a3;
    __syncthreads();
    for (int s = 128; s > 0; s >>= 1) {
        if (tid < s) {
            red[tid][0] += red[tid + s][0]; red[tid][1] += red[tid + s][1];
            red[tid][2] += red[tid + s][2]; red[tid][3] += red[tid + s][3];
        }
        __syncthreads();
    }
    if (tid < 4) {
        float v = red[0][tid] + bl2[tid];
        out[r * 4 + tid] = LRELU(v);
    }
}

// ---------------- launch ----------------
extern "C" void kernel_launch(void* const* d_in, const int* in_sizes, int n_in,
                              void* d_out, int out_size, void* d_ws, size_t ws_size,
                              hipStream_t stream)
{
    const int*   x     = (const int*)d_in[0];
    const int*   ei    = (const int*)d_in[1];
    const int*   batch = (const int*)d_in[2];
    const float* emb   = (const float*)d_in[3];
    const float* W1    = (const float*)d_in[4];
    const float* b1    = (const float*)d_in[5];
    const float* W2    = (const float*)d_in[6];
    const float* b2    = (const float*)d_in[7];
    const float* Wl1   = (const float*)d_in[8];
    const float* bl1   = (const float*)d_in[9];
    const float* Wl2   = (const float*)d_in[10];
    const float* bl2   = (const float*)d_in[11];
    float* out = (float*)d_out;

    const int* esrc = ei;
    const int* edst = ei + Ee;

    const size_t MiB = 1ull << 20;
    char* W = (char*)d_ws;
    short* Ah0b = (short*)(W + 64 * MiB);   // [8192,4096] bf16, 64 MiB
    short* W2t  = (short*)(W + 96 * MiB);   // [6144,6144] bf16, 72 MiB (after GEMM1)
    short* W1t  = (short*)(W + 128 * MiB);  // [6144,4096] bf16, 48 MiB
    short* h1b  = (short*)(W + 176 * MiB);  // [8192,6144] bf16, 96 MiB
    short* Ah1b = (short*)(W + 0);          // [8192,6144] bf16, 96 MiB (after GEMM1)
    short* h2b  = h1b;                      // reuse
    float* part = (float*)(W + 0);          // [24][64][3072] f32 (after pool)
    float* gpart = (float*)(W + 128 * MiB); // [4][64][6144] f32, 6 MB (W1t dead after GEMM1)
    char* S = W + 272 * MiB;
    int*   indeg  = (int*)(S);                 // 32 KB
    int*   fillc  = (int*)(S + 32 * 1024);     // 32 KB (adjacent -> single memset)
    int*   rowptr = (int*)(S + 64 * 1024);
    float* dinv   = (float*)(S + 96 * 1024);
    int*   csr    = (int*)(S + 128 * 1024);
    int*   bptr   = (int*)(S + 256 * 1024);
    float* g      = (float*)(S + 320 * 1024);
    float* g1     = (float*)(S + 320 * 1024 + 2 * MiB);

    hipMemsetAsync(indeg, 0, 64 * 1024, stream);   // indeg + fillc in one shot

    k_pre<<<125 + (Nn + 255) / 256, 256, 0, stream>>>(edst, indeg, batch, bptr);
    k_scan<<<1, 1024, 0, stream>>>(indeg, rowptr, dinv, Nn);
    k_fill<<<(Ee + 255) / 256, 256, 0, stream>>>(esrc, edst, rowptr, fillc, csr);

    const int nbx = K2 / GBN;               // 24
    const int nwg = nbx * (Mp / GBM);       // 24*32 = 768, % 8 == 0

    k_gagg<<<Nn, 256, 0, stream>>>(x, emb, dinv, rowptr, csr, Ah0b);
    k_transpose<<<dim3(K1 / 32, K2 / 32), 256, 0, stream>>>(W1, W1t, 4000, 6000, K1, K2);
    k_gemm8w<<<nwg, 512, 0, stream>>>(Ah0b, W1t, h1b, b1, K1, K1L, K2, 6000, nbx);

    k_transpose<<<dim3(K2 / 32, K2 / 32), 256, 0, stream>>>(W2, W2t, 6000, 6000, K2, K2);
    k_agg<3><<<Nn, 256, 0, stream>>>(h1b, Ah1b, dinv, rowptr, csr, K2);
    k_gemm8w<<<nwg, 512, 0, stream>>>(Ah1b, W2t, h2b, b2, K2, K2L, K2, 6000, nbx);

    k_pool_part<<<dim3(K2 / 2048, Bb, 4), 256, 0, stream>>>(h2b, bptr, gpart, K2);
    k_pool_red<<<(Bb * K2 + 255) / 256, 256, 0, stream>>>(gpart, g);
    k_lin1_part<<<dim3(L1p / 64, NCH), 256, 0, stream>>>(g, Wl1, part);
    k_lin1_red<<<(64 * 3000 + 255) / 256, 256, 0, stream>>>(part, bl1, g1);
    k_lin2<<<Bb, 256, 0, stream>>>(g1, Wl2, bl2, out);
}